// Round 10
// baseline (146.072 us; speedup 1.0000x reference)
//
#include <hip/hip_runtime.h>
#include <math.h>

#define NN 1024
#define B_C 64
#define L_C 160000
#define T_C 622
#define F_C 513
#define TT 16
#define NTILE ((T_C + TT - 1) / TT)   // 39
#define WIN_MIN_C (1024.0f / 20.0f)
#define WIN_MAX_C 1024.0f
#define TWO_PI 6.28318530717958647692f

typedef unsigned uv2 __attribute__((ext_vector_type(2)));

__device__ __forceinline__ int brev6(int x) {
    return ((x & 1) << 5) | ((x & 2) << 3) | ((x & 4) << 1) |
           ((x & 8) >> 1) | ((x & 16) >> 3) | ((x & 32) >> 5);
}

// ---- lane-exchange helpers: VALU-rate (permlane/DPP) where possible ----
__device__ __forceinline__ float lane_xor32(float v, int l) {
#if __has_builtin(__builtin_amdgcn_permlane32_swap)
    uv2 r = __builtin_amdgcn_permlane32_swap(__float_as_uint(v), __float_as_uint(v),
                                             false, false);
    return __uint_as_float((l & 32) ? r.x : r.y);
#else
    return __shfl_xor(v, 32, 64);
#endif
}
__device__ __forceinline__ float lane_xor16(float v, int l) {
#if __has_builtin(__builtin_amdgcn_permlane16_swap)
    uv2 r = __builtin_amdgcn_permlane16_swap(__float_as_uint(v), __float_as_uint(v),
                                             false, false);
    return __uint_as_float((l & 16) ? r.x : r.y);
#else
    return __shfl_xor(v, 16, 64);
#endif
}
__device__ __forceinline__ float lane_xor8(float v) {   // row_ror:8 == xor8
    return __int_as_float(__builtin_amdgcn_update_dpp(
        __float_as_int(v), __float_as_int(v), 0x128, 0xF, 0xF, false));
}
__device__ __forceinline__ float lane_xor4(float v) {   // ds_swizzle xor4
    return __int_as_float(__builtin_amdgcn_ds_swizzle(__float_as_int(v), 0x101F));
}
__device__ __forceinline__ float lane_xor2(float v) {   // quad_perm [2,3,0,1]
    return __int_as_float(__builtin_amdgcn_update_dpp(
        __float_as_int(v), __float_as_int(v), 0x4E, 0xF, 0xF, false));
}
__device__ __forceinline__ float lane_xor1(float v) {   // quad_perm [1,0,3,2]
    return __int_as_float(__builtin_amdgcn_update_dpp(
        __float_as_int(v), __float_as_int(v), 0xB1, 0xF, 0xF, false));
}
__device__ __forceinline__ float lane_mirror16(float v) { // row_mirror == xor15
    return __int_as_float(__builtin_amdgcn_update_dpp(
        __float_as_int(v), __float_as_int(v), 0x140, 0xF, 0xF, false));
}
__device__ __forceinline__ float lane_xor63(float v, int l) {
    return lane_xor32(lane_xor16(lane_mirror16(v), l), l);  // 15^16^32 = 63
}
__device__ __forceinline__ float fast_sqrtf(float x) {
#if __has_builtin(__builtin_amdgcn_sqrtf)
    return __builtin_amdgcn_sqrtf(x);
#else
    return sqrtf(x);
#endif
}

// ---------------- Kernel A: per-frame normalized Hann taps ----------------
__global__ __launch_bounds__(256) void win_kernel(
    const float* __restrict__ win_length,
    const float* __restrict__ strides,
    const float* __restrict__ win_pow,
    float* __restrict__ tap)   // [T_C][NN]
{
    const int t = blockIdx.x;
    const int tid = threadIdx.x;

    const float wl = fminf(fmaxf(win_length[0], WIN_MIN_C), WIN_MAX_C);
    const float st = fminf(fmaxf(strides[0], 0.0f), WIN_MAX_C);
    const float wp = win_pow[0];

    const float frame = (float)t * st;
    const float frac = frame - floorf(frame);

    const float hi = ceilf(((float)NN - 1.0f + wl) * 0.5f);
    const float lo = floorf(((float)NN - 1.0f - wl) * 0.5f);
    const float off = (wl - (float)NN + 1.0f) * 0.5f;
    const float inv_wl = 1.0f / wl;

    __shared__ float s_tap[NN];
    __shared__ float s_red[256];

    float local = 0.0f;
    for (int n = tid; n < NN; n += 256) {
        float base = (float)n - frac;
        float v = 0.5f - 0.5f * cosf(TWO_PI * (base + off) * inv_wl);
        if (base >= hi || base <= lo) v = 0.0f;
        s_tap[n] = v;
        local += v;
    }
    s_red[tid] = local;
    __syncthreads();
    for (int s = 128; s > 0; s >>= 1) {
        if (tid < s) s_red[tid] += s_red[tid + s];
        __syncthreads();
    }
    const float inv_sum = 1.0f / s_red[0];
    const bool pow_one = (wp == 1.0f);
    for (int n = tid; n < NN; n += 256) {
        float v = s_tap[n] * inv_sum;
        if (!pow_one) v = powf(v, wp);
        tap[t * NN + n] = v;
    }
}

// ---- 16-point DIF FFT over a register array (compile-time indices) ----
#define FFT16(vr, vi)                                                         \
    _Pragma("unroll")                                                         \
    for (int s = 0; s < 4; ++s) {                                             \
        const int half_ = (16 >> s) >> 1;                                     \
        _Pragma("unroll")                                                     \
        for (int b0 = 0; b0 < 16; b0 += (16 >> s)) {                          \
            _Pragma("unroll")                                                 \
            for (int j = 0; j < 8; ++j) {                                     \
                if (j < half_) {                                              \
                    const int i0 = b0 + j, i1 = b0 + j + half_;               \
                    const float ur = vr[i0], ui = vi[i0];                     \
                    const float wr = vr[i1], wi = vi[i1];                     \
                    vr[i0] = ur + wr; vi[i0] = ui + wi;                       \
                    const float dr = ur - wr, di = ui - wi;                   \
                    const float c = C16[j << s], ss = S16[j << s];            \
                    vr[i1] = dr * c - di * ss;                                \
                    vi[i1] = dr * ss + di * c;                                \
                }                                                             \
            }                                                                 \
        }                                                                     \
    }

// --- Kernel B: 4 waves/block, TWO packed FFTs (4 frames) per wave ---
__global__ __launch_bounds__(256, 4) void fftw_kernel(
    const float* __restrict__ x,        // [B_C][L_C]
    const float* __restrict__ strides,
    const float* __restrict__ tap,      // [T_C][NN]
    float* __restrict__ out)            // [B_C][F_C][T_C]
{
    const int tile = blockIdx.x % NTILE;
    const int b = blockIdx.x / NTILE;
    const int t0 = tile * TT;
    const int tid = threadIdx.x;
    const int w = tid >> 6;      // wave id 0..3 -> frame quad
    const int l = tid & 63;      // lane

    const float st = fminf(fmaxf(strides[0], 0.0f), WIN_MAX_C);
    const float* xb = x + (size_t)b * L_C;

    __shared__ float mag[TT][F_C + 16];   // 529-float rows: stride%32=17, coprime

    const int bl = brev6(l);
    const int l2 = brev6((64 - bl) & 63);   // unpack partner lane for k1==0 reg

    constexpr int BR4[16]     = {0,8,4,12,2,10,6,14,1,9,5,13,3,11,7,15};
    constexpr int PARTNER[16] = {0,1,3,2,7,6,5,4,15,14,13,12,11,10,9,8};
    constexpr float C16[8] = {1.0f, 0.92387953251f, 0.70710678119f, 0.38268343236f,
                              0.0f, -0.38268343236f, -0.70710678119f, -0.92387953251f};
    constexpr float S16[8] = {0.0f, -0.38268343236f, -0.70710678119f, -0.92387953251f,
                              -1.0f, -0.92387953251f, -0.70710678119f, -0.38268343236f};

    // stream 0: frames tA0 (re), tB0 (im); stream 1: frames tA1, tB1
    const int tA0 = t0 + 4 * w;
    const int tB0 = tA0 + 1, tA1 = tA0 + 2, tB1 = tA0 + 3;
    const bool hasA0 = (tA0 < T_C), hasB0 = (tB0 < T_C);
    const bool hasA1 = (tA1 < T_C), hasB1 = (tB1 < T_C);
    const int idxA0 = hasA0 ? (int)floorf((float)tA0 * st) : 0;
    const int idxB0 = hasB0 ? (int)floorf((float)tB0 * st) : 0;
    const int idxA1 = hasA1 ? (int)floorf((float)tA1 * st) : 0;
    const int idxB1 = hasB1 ? (int)floorf((float)tB1 * st) : 0;
    const float* tpA0 = tap + (size_t)tA0 * NN;
    const float* tpB0 = tap + (size_t)tB0 * NN;
    const float* tpA1 = tap + (size_t)tA1 * NN;
    const float* tpB1 = tap + (size_t)tB1 * NN;

    float v0r[16], v0i[16], v1r[16], v1i[16];

    // ---- load + taper; wave-uniform in-bounds fast path
    const bool ok = hasA0 && hasB0 && hasA1 && hasB1 &&
                    (idxA0 >= 0) && (idxB1 + NN <= L_C);
    if (ok) {
#pragma unroll
        for (int r = 0; r < 16; ++r) {
            const int n = r * 64 + l;
            v0r[r] = xb[idxA0 + n] * tpA0[n];
            v0i[r] = xb[idxB0 + n] * tpB0[n];
            v1r[r] = xb[idxA1 + n] * tpA1[n];
            v1i[r] = xb[idxB1 + n] * tpB1[n];
        }
    } else {
#pragma unroll
        for (int r = 0; r < 16; ++r) {
            const int n = r * 64 + l;
            float a0 = 0.0f, b0v = 0.0f, a1 = 0.0f, b1v = 0.0f;
            if (hasA0) { int i_ = idxA0 + n; a0  = (i_ >= 0 && i_ < L_C) ? xb[i_] * tpA0[n] : 0.0f; }
            if (hasB0) { int i_ = idxB0 + n; b0v = (i_ >= 0 && i_ < L_C) ? xb[i_] * tpB0[n] : 0.0f; }
            if (hasA1) { int i_ = idxA1 + n; a1  = (i_ >= 0 && i_ < L_C) ? xb[i_] * tpA1[n] : 0.0f; }
            if (hasB1) { int i_ = idxB1 + n; b1v = (i_ >= 0 && i_ < L_C) ? xb[i_] * tpB1[n] : 0.0f; }
            v0r[r] = a0; v0i[r] = b0v;
            v1r[r] = a1; v1i[r] = b1v;
        }
    }

    // ---- 16-point DIF FFT over registers, both streams
    FFT16(v0r, v0i)
    FFT16(v1r, v1i)

    // ---- twiddle W_1024^(l * k1): powers via doubling tree, shared by streams
    {
        float c1, s1;
        __sincosf(-(TWO_PI / 1024.0f) * (float)l, &s1, &c1);
        const float c2 = c1 * c1 - s1 * s1,  s2 = 2.0f * c1 * s1;
        const float c4 = c2 * c2 - s2 * s2,  s4 = 2.0f * c2 * s2;
        const float c8 = c4 * c4 - s4 * s4,  s8 = 2.0f * c4 * s4;
        const float c3 = c1 * c2 - s1 * s2,  s3 = c1 * s2 + s1 * c2;
        const float c5 = c1 * c4 - s1 * s4,  s5 = c1 * s4 + s1 * c4;
        const float c6 = c2 * c4 - s2 * s4,  s6 = c2 * s4 + s2 * c4;
        const float c7 = c3 * c4 - s3 * s4,  s7 = c3 * s4 + s3 * c4;
        const float c9  = c1 * c8 - s1 * s8, s9  = c1 * s8 + s1 * c8;
        const float c10 = c2 * c8 - s2 * s8, s10 = c2 * s8 + s2 * c8;
        const float c11 = c3 * c8 - s3 * s8, s11 = c3 * s8 + s3 * c8;
        const float c12 = c4 * c8 - s4 * s8, s12 = c4 * s8 + s4 * c8;
        const float c13 = c5 * c8 - s5 * s8, s13 = c5 * s8 + s5 * c8;
        const float c14 = c6 * c8 - s6 * s8, s14 = c6 * s8 + s6 * c8;
        const float c15 = c7 * c8 - s7 * s8, s15 = c7 * s8 + s7 * c8;
#define TW(K) { const int i_ = BR4[K];                                         \
                { const float ar = v0r[i_], ai = v0i[i_];                      \
                  v0r[i_] = ar * c##K - ai * s##K;                             \
                  v0i[i_] = ar * s##K + ai * c##K; }                           \
                { const float ar = v1r[i_], ai = v1i[i_];                      \
                  v1r[i_] = ar * c##K - ai * s##K;                             \
                  v1i[i_] = ar * s##K + ai * c##K; } }
        TW(1) TW(2) TW(3) TW(4) TW(5) TW(6) TW(7) TW(8)
        TW(9) TW(10) TW(11) TW(12) TW(13) TW(14) TW(15)
#undef TW
    }

    // ---- 64-point DIF FFT across lanes; shared stage constants, 2 streams
#pragma unroll
    for (int s = 0; s < 6; ++s) {
        const int half = 32 >> s;
        const bool low = (l & (2 * half - 1)) < half;
        const float sgn = low ? 1.0f : -1.0f;
        const int j = l & (half - 1);
        float sv, cv;
        __sincosf(-(TWO_PI * (float)j) / (float)(2 * half), &sv, &cv);
        const float tc = low ? 1.0f : cv;
        const float ts = low ? 0.0f : sv;
        // stream 0
        {
            float pr[16], pi[16];
#pragma unroll
            for (int i = 0; i < 16; ++i) {
                if (s == 0)      { pr[i] = lane_xor32(v0r[i], l); pi[i] = lane_xor32(v0i[i], l); }
                else if (s == 1) { pr[i] = lane_xor16(v0r[i], l); pi[i] = lane_xor16(v0i[i], l); }
                else if (s == 2) { pr[i] = lane_xor8(v0r[i]);     pi[i] = lane_xor8(v0i[i]); }
                else if (s == 3) { pr[i] = lane_xor4(v0r[i]);     pi[i] = lane_xor4(v0i[i]); }
                else if (s == 4) { pr[i] = lane_xor2(v0r[i]);     pi[i] = lane_xor2(v0i[i]); }
                else             { pr[i] = lane_xor1(v0r[i]);     pi[i] = lane_xor1(v0i[i]); }
            }
#pragma unroll
            for (int i = 0; i < 16; ++i) {
                const float sr = fmaf(sgn, v0r[i], pr[i]);
                const float si = fmaf(sgn, v0i[i], pi[i]);
                v0r[i] = sr * tc - si * ts;
                v0i[i] = sr * ts + si * tc;
            }
        }
        // stream 1
        {
            float pr[16], pi[16];
#pragma unroll
            for (int i = 0; i < 16; ++i) {
                if (s == 0)      { pr[i] = lane_xor32(v1r[i], l); pi[i] = lane_xor32(v1i[i], l); }
                else if (s == 1) { pr[i] = lane_xor16(v1r[i], l); pi[i] = lane_xor16(v1i[i], l); }
                else if (s == 2) { pr[i] = lane_xor8(v1r[i]);     pi[i] = lane_xor8(v1i[i]); }
                else if (s == 3) { pr[i] = lane_xor4(v1r[i]);     pi[i] = lane_xor4(v1i[i]); }
                else if (s == 4) { pr[i] = lane_xor2(v1r[i]);     pi[i] = lane_xor2(v1i[i]); }
                else             { pr[i] = lane_xor1(v1r[i]);     pi[i] = lane_xor1(v1i[i]); }
            }
#pragma unroll
            for (int i = 0; i < 16; ++i) {
                const float sr = fmaf(sgn, v1r[i], pr[i]);
                const float si = fmaf(sgn, v1i[i], pi[i]);
                v1r[i] = sr * tc - si * ts;
                v1i[i] = sr * ts + si * tc;
            }
        }
    }
    // now (lane l, reg i) holds X[k], k = BR4[i] + 16*brev6(l), per stream

    // ---- conjugate-symmetry unpack + magnitudes -> mag LDS (both streams)
    {
        float y0r[16], y0i[16], y1r[16], y1i[16];
        y0r[0] = __shfl(v0r[0], l2, 64);
        y0i[0] = __shfl(v0i[0], l2, 64);
        y1r[0] = __shfl(v1r[0], l2, 64);
        y1i[0] = __shfl(v1i[0], l2, 64);
#pragma unroll
        for (int i = 1; i < 16; ++i) {
            y0r[i] = lane_xor63(v0r[PARTNER[i]], l);
            y0i[i] = lane_xor63(v0i[PARTNER[i]], l);
            y1r[i] = lane_xor63(v1r[PARTNER[i]], l);
            y1i[i] = lane_xor63(v1i[PARTNER[i]], l);
        }
        const int row = 4 * w;
#pragma unroll
        for (int i = 0; i < 16; ++i) {
            const int k = BR4[i] + 16 * bl;
            if (k <= 512) {
                const int ka = k + (k >> 5);
                {
                    const float sa = v0r[i] + y0r[i], sb = v0i[i] - y0i[i];
                    const float ua = v0i[i] + y0i[i], ub = y0r[i] - v0r[i];
                    if (hasA0) mag[row + 0][ka] = 0.5f * fast_sqrtf(fmaf(sa, sa, sb * sb));
                    if (hasB0) mag[row + 1][ka] = 0.5f * fast_sqrtf(fmaf(ua, ua, ub * ub));
                }
                {
                    const float sa = v1r[i] + y1r[i], sb = v1i[i] - y1i[i];
                    const float ua = v1i[i] + y1i[i], ub = y1r[i] - v1r[i];
                    if (hasA1) mag[row + 2][ka] = 0.5f * fast_sqrtf(fmaf(sa, sa, sb * sb));
                    if (hasB1) mag[row + 3][ka] = 0.5f * fast_sqrtf(fmaf(ua, ua, ub * ub));
                }
            }
        }
    }

    __syncthreads();

    // ---- coalesced write-out: rows of 16 consecutive t per f
    if (t0 + TT <= T_C) {
#pragma unroll 4
        for (int e = tid; e < F_C * TT; e += 256) {
            const int f = e >> 4;
            const int tt = e & 15;
            out[((size_t)b * F_C + f) * T_C + t0 + tt] = mag[tt][f + (f >> 5)];
        }
    } else {
        for (int e = tid; e < F_C * TT; e += 256) {
            const int f = e >> 4;
            const int tt = e & 15;
            const int t = t0 + tt;
            if (t < T_C)
                out[((size_t)b * F_C + f) * T_C + t] = mag[tt][f + (f >> 5)];
        }
    }
}

extern "C" void kernel_launch(void* const* d_in, const int* in_sizes, int n_in,
                              void* d_out, int out_size, void* d_ws, size_t ws_size,
                              hipStream_t stream) {
    const float* x   = (const float*)d_in[0];
    const float* wl  = (const float*)d_in[1];
    const float* st  = (const float*)d_in[2];
    const float* wp  = (const float*)d_in[3];
    float* out = (float*)d_out;
    float* tap = (float*)d_ws;   // T_C*NN floats ~ 2.55 MB

    win_kernel<<<dim3(T_C), dim3(256), 0, stream>>>(wl, st, wp, tap);
    fftw_kernel<<<dim3(B_C * NTILE), dim3(256), 0, stream>>>(x, st, tap, out);
}

// Round 11
// 117.026 us; speedup vs baseline: 1.2482x; 1.2482x over previous
//
#include <hip/hip_runtime.h>
#include <math.h>

#define NN 1024
#define B_C 64
#define L_C 160000
#define T_C 622
#define F_C 513
#define TT 16
#define NTILE ((T_C + TT - 1) / TT)   // 39
#define WIN_MIN_C (1024.0f / 20.0f)
#define WIN_MAX_C 1024.0f
#define TWO_PI 6.28318530717958647692f

typedef unsigned uv2 __attribute__((ext_vector_type(2)));

__device__ __forceinline__ int brev6(int x) {
    return ((x & 1) << 5) | ((x & 2) << 3) | ((x & 4) << 1) |
           ((x & 8) >> 1) | ((x & 16) >> 3) | ((x & 32) >> 5);
}

// ---- lane-exchange helpers: VALU-rate (permlane/DPP) where possible ----
__device__ __forceinline__ float lane_xor32(float v, int l) {
#if __has_builtin(__builtin_amdgcn_permlane32_swap)
    uv2 r = __builtin_amdgcn_permlane32_swap(__float_as_uint(v), __float_as_uint(v),
                                             false, false);
    return __uint_as_float((l & 32) ? r.x : r.y);
#else
    return __shfl_xor(v, 32, 64);
#endif
}
__device__ __forceinline__ float lane_xor16(float v, int l) {
#if __has_builtin(__builtin_amdgcn_permlane16_swap)
    uv2 r = __builtin_amdgcn_permlane16_swap(__float_as_uint(v), __float_as_uint(v),
                                             false, false);
    return __uint_as_float((l & 16) ? r.x : r.y);
#else
    return __shfl_xor(v, 16, 64);
#endif
}
__device__ __forceinline__ float lane_xor8(float v) {   // row_ror:8 == xor8
    return __int_as_float(__builtin_amdgcn_update_dpp(
        __float_as_int(v), __float_as_int(v), 0x128, 0xF, 0xF, false));
}
__device__ __forceinline__ float lane_xor4(float v) {   // ds_swizzle xor4
    return __int_as_float(__builtin_amdgcn_ds_swizzle(__float_as_int(v), 0x101F));
}
__device__ __forceinline__ float lane_xor2(float v) {   // quad_perm [2,3,0,1]
    return __int_as_float(__builtin_amdgcn_update_dpp(
        __float_as_int(v), __float_as_int(v), 0x4E, 0xF, 0xF, false));
}
__device__ __forceinline__ float lane_xor1(float v) {   // quad_perm [1,0,3,2]
    return __int_as_float(__builtin_amdgcn_update_dpp(
        __float_as_int(v), __float_as_int(v), 0xB1, 0xF, 0xF, false));
}
__device__ __forceinline__ float lane_mirror16(float v) { // row_mirror == xor15
    return __int_as_float(__builtin_amdgcn_update_dpp(
        __float_as_int(v), __float_as_int(v), 0x140, 0xF, 0xF, false));
}
__device__ __forceinline__ float lane_xor63(float v, int l) {
    return lane_xor32(lane_xor16(lane_mirror16(v), l), l);  // 15^16^32 = 63
}
__device__ __forceinline__ float fast_sqrtf(float x) {
#if __has_builtin(__builtin_amdgcn_sqrtf)
    return __builtin_amdgcn_sqrtf(x);
#else
    return sqrtf(x);
#endif
}

// ---------------- Kernel A: per-frame normalized Hann taps ----------------
__global__ __launch_bounds__(256) void win_kernel(
    const float* __restrict__ win_length,
    const float* __restrict__ strides,
    const float* __restrict__ win_pow,
    float* __restrict__ tap)   // [T_C][NN]
{
    const int t = blockIdx.x;
    const int tid = threadIdx.x;

    const float wl = fminf(fmaxf(win_length[0], WIN_MIN_C), WIN_MAX_C);
    const float st = fminf(fmaxf(strides[0], 0.0f), WIN_MAX_C);
    const float wp = win_pow[0];

    const float frame = (float)t * st;
    const float frac = frame - floorf(frame);

    const float hi = ceilf(((float)NN - 1.0f + wl) * 0.5f);
    const float lo = floorf(((float)NN - 1.0f - wl) * 0.5f);
    const float off = (wl - (float)NN + 1.0f) * 0.5f;
    const float inv_wl = 1.0f / wl;

    __shared__ float s_tap[NN];
    __shared__ float s_red[256];

    float local = 0.0f;
    for (int n = tid; n < NN; n += 256) {
        float base = (float)n - frac;
        float v = 0.5f - 0.5f * cosf(TWO_PI * (base + off) * inv_wl);
        if (base >= hi || base <= lo) v = 0.0f;
        s_tap[n] = v;
        local += v;
    }
    s_red[tid] = local;
    __syncthreads();
    for (int s = 128; s > 0; s >>= 1) {
        if (tid < s) s_red[tid] += s_red[tid + s];
        __syncthreads();
    }
    const float inv_sum = 1.0f / s_red[0];
    const bool pow_one = (wp == 1.0f);
    for (int n = tid; n < NN; n += 256) {
        float v = s_tap[n] * inv_sum;
        if (!pow_one) v = powf(v, wp);
        tap[t * NN + n] = v;
    }
}

// ---- 16-point DIF FFT over a register array (compile-time indices) ----
#define FFT16(vr, vi)                                                         \
    _Pragma("unroll")                                                         \
    for (int s = 0; s < 4; ++s) {                                             \
        const int half_ = (16 >> s) >> 1;                                     \
        _Pragma("unroll")                                                     \
        for (int b0 = 0; b0 < 16; b0 += (16 >> s)) {                          \
            _Pragma("unroll")                                                 \
            for (int j = 0; j < 8; ++j) {                                     \
                if (j < half_) {                                              \
                    const int i0 = b0 + j, i1 = b0 + j + half_;               \
                    const float ur = vr[i0], ui = vi[i0];                     \
                    const float wr = vr[i1], wi = vi[i1];                     \
                    vr[i0] = ur + wr; vi[i0] = ui + wi;                       \
                    const float dr = ur - wr, di = ui - wi;                   \
                    const float c = C16[j << s], ss = S16[j << s];            \
                    vr[i1] = dr * c - di * ss;                                \
                    vi[i1] = dr * ss + di * c;                                \
                }                                                             \
            }                                                                 \
        }                                                                     \
    }

// --- Kernel B: 4 waves/block, TWO packed FFTs (4 frames) per wave ---
// (256, 3): VGPR cap ~168 -> fits the ~130-live 2-stream state, NO SPILLS.
__global__ __launch_bounds__(256, 3) void fftw_kernel(
    const float* __restrict__ x,        // [B_C][L_C]
    const float* __restrict__ strides,
    const float* __restrict__ tap,      // [T_C][NN]
    float* __restrict__ out)            // [B_C][F_C][T_C]
{
    const int tile = blockIdx.x % NTILE;
    const int b = blockIdx.x / NTILE;
    const int t0 = tile * TT;
    const int tid = threadIdx.x;
    const int w = tid >> 6;      // wave id 0..3 -> frame quad
    const int l = tid & 63;      // lane

    const float st = fminf(fmaxf(strides[0], 0.0f), WIN_MAX_C);
    const float* xb = x + (size_t)b * L_C;

    __shared__ float mag[TT][F_C + 16];   // 529-float rows: stride%32=17, coprime

    const int bl = brev6(l);
    const int l2 = brev6((64 - bl) & 63);   // unpack partner lane for k1==0 reg

    constexpr int BR4[16]     = {0,8,4,12,2,10,6,14,1,9,5,13,3,11,7,15};
    constexpr int PARTNER[16] = {0,1,3,2,7,6,5,4,15,14,13,12,11,10,9,8};
    constexpr float C16[8] = {1.0f, 0.92387953251f, 0.70710678119f, 0.38268343236f,
                              0.0f, -0.38268343236f, -0.70710678119f, -0.92387953251f};
    constexpr float S16[8] = {0.0f, -0.38268343236f, -0.70710678119f, -0.92387953251f,
                              -1.0f, -0.92387953251f, -0.70710678119f, -0.38268343236f};

    // stream 0: frames tA0 (re), tB0 (im); stream 1: frames tA1, tB1
    const int tA0 = t0 + 4 * w;
    const int tB0 = tA0 + 1, tA1 = tA0 + 2, tB1 = tA0 + 3;
    const bool hasA0 = (tA0 < T_C), hasB0 = (tB0 < T_C);
    const bool hasA1 = (tA1 < T_C), hasB1 = (tB1 < T_C);
    const int idxA0 = hasA0 ? (int)floorf((float)tA0 * st) : 0;
    const int idxB0 = hasB0 ? (int)floorf((float)tB0 * st) : 0;
    const int idxA1 = hasA1 ? (int)floorf((float)tA1 * st) : 0;
    const int idxB1 = hasB1 ? (int)floorf((float)tB1 * st) : 0;
    const float* tpA0 = tap + (size_t)tA0 * NN;
    const float* tpB0 = tap + (size_t)tB0 * NN;
    const float* tpA1 = tap + (size_t)tA1 * NN;
    const float* tpB1 = tap + (size_t)tB1 * NN;

    float v0r[16], v0i[16], v1r[16], v1i[16];

    // ---- load + taper; wave-uniform in-bounds fast path
    const bool ok = hasA0 && hasB0 && hasA1 && hasB1 &&
                    (idxA0 >= 0) && (idxB1 + NN <= L_C);
    if (ok) {
#pragma unroll
        for (int r = 0; r < 16; ++r) {
            const int n = r * 64 + l;
            v0r[r] = xb[idxA0 + n] * tpA0[n];
            v0i[r] = xb[idxB0 + n] * tpB0[n];
            v1r[r] = xb[idxA1 + n] * tpA1[n];
            v1i[r] = xb[idxB1 + n] * tpB1[n];
        }
    } else {
#pragma unroll
        for (int r = 0; r < 16; ++r) {
            const int n = r * 64 + l;
            float a0 = 0.0f, b0v = 0.0f, a1 = 0.0f, b1v = 0.0f;
            if (hasA0) { int i_ = idxA0 + n; a0  = (i_ >= 0 && i_ < L_C) ? xb[i_] * tpA0[n] : 0.0f; }
            if (hasB0) { int i_ = idxB0 + n; b0v = (i_ >= 0 && i_ < L_C) ? xb[i_] * tpB0[n] : 0.0f; }
            if (hasA1) { int i_ = idxA1 + n; a1  = (i_ >= 0 && i_ < L_C) ? xb[i_] * tpA1[n] : 0.0f; }
            if (hasB1) { int i_ = idxB1 + n; b1v = (i_ >= 0 && i_ < L_C) ? xb[i_] * tpB1[n] : 0.0f; }
            v0r[r] = a0; v0i[r] = b0v;
            v1r[r] = a1; v1i[r] = b1v;
        }
    }

    // ---- 16-point DIF FFT over registers, both streams
    FFT16(v0r, v0i)
    FFT16(v1r, v1i)

    // ---- twiddle W_1024^(l * k1): powers via doubling tree, shared by streams
    {
        float c1, s1;
        __sincosf(-(TWO_PI / 1024.0f) * (float)l, &s1, &c1);
        const float c2 = c1 * c1 - s1 * s1,  s2 = 2.0f * c1 * s1;
        const float c4 = c2 * c2 - s2 * s2,  s4 = 2.0f * c2 * s2;
        const float c8 = c4 * c4 - s4 * s4,  s8 = 2.0f * c4 * s4;
        const float c3 = c1 * c2 - s1 * s2,  s3 = c1 * s2 + s1 * c2;
        const float c5 = c1 * c4 - s1 * s4,  s5 = c1 * s4 + s1 * c4;
        const float c6 = c2 * c4 - s2 * s4,  s6 = c2 * s4 + s2 * c4;
        const float c7 = c3 * c4 - s3 * s4,  s7 = c3 * s4 + s3 * c4;
        const float c9  = c1 * c8 - s1 * s8, s9  = c1 * s8 + s1 * c8;
        const float c10 = c2 * c8 - s2 * s8, s10 = c2 * s8 + s2 * c8;
        const float c11 = c3 * c8 - s3 * s8, s11 = c3 * s8 + s3 * c8;
        const float c12 = c4 * c8 - s4 * s8, s12 = c4 * s8 + s4 * c8;
        const float c13 = c5 * c8 - s5 * s8, s13 = c5 * s8 + s5 * c8;
        const float c14 = c6 * c8 - s6 * s8, s14 = c6 * s8 + s6 * c8;
        const float c15 = c7 * c8 - s7 * s8, s15 = c7 * s8 + s7 * c8;
#define TW(K) { const int i_ = BR4[K];                                         \
                { const float ar = v0r[i_], ai = v0i[i_];                      \
                  v0r[i_] = ar * c##K - ai * s##K;                             \
                  v0i[i_] = ar * s##K + ai * c##K; }                           \
                { const float ar = v1r[i_], ai = v1i[i_];                      \
                  v1r[i_] = ar * c##K - ai * s##K;                             \
                  v1i[i_] = ar * s##K + ai * c##K; } }
        TW(1) TW(2) TW(3) TW(4) TW(5) TW(6) TW(7) TW(8)
        TW(9) TW(10) TW(11) TW(12) TW(13) TW(14) TW(15)
#undef TW
    }

    // ---- 64-point DIF FFT across lanes; shared stage constants, 2 streams
#pragma unroll
    for (int s = 0; s < 6; ++s) {
        const int half = 32 >> s;
        const bool low = (l & (2 * half - 1)) < half;
        const float sgn = low ? 1.0f : -1.0f;
        const int j = l & (half - 1);
        float sv, cv;
        __sincosf(-(TWO_PI * (float)j) / (float)(2 * half), &sv, &cv);
        const float tc = low ? 1.0f : cv;
        const float ts = low ? 0.0f : sv;
        // stream 0
        {
            float pr[16], pi[16];
#pragma unroll
            for (int i = 0; i < 16; ++i) {
                if (s == 0)      { pr[i] = lane_xor32(v0r[i], l); pi[i] = lane_xor32(v0i[i], l); }
                else if (s == 1) { pr[i] = lane_xor16(v0r[i], l); pi[i] = lane_xor16(v0i[i], l); }
                else if (s == 2) { pr[i] = lane_xor8(v0r[i]);     pi[i] = lane_xor8(v0i[i]); }
                else if (s == 3) { pr[i] = lane_xor4(v0r[i]);     pi[i] = lane_xor4(v0i[i]); }
                else if (s == 4) { pr[i] = lane_xor2(v0r[i]);     pi[i] = lane_xor2(v0i[i]); }
                else             { pr[i] = lane_xor1(v0r[i]);     pi[i] = lane_xor1(v0i[i]); }
            }
#pragma unroll
            for (int i = 0; i < 16; ++i) {
                const float sr = fmaf(sgn, v0r[i], pr[i]);
                const float si = fmaf(sgn, v0i[i], pi[i]);
                v0r[i] = sr * tc - si * ts;
                v0i[i] = sr * ts + si * tc;
            }
        }
        // stream 1
        {
            float pr[16], pi[16];
#pragma unroll
            for (int i = 0; i < 16; ++i) {
                if (s == 0)      { pr[i] = lane_xor32(v1r[i], l); pi[i] = lane_xor32(v1i[i], l); }
                else if (s == 1) { pr[i] = lane_xor16(v1r[i], l); pi[i] = lane_xor16(v1i[i], l); }
                else if (s == 2) { pr[i] = lane_xor8(v1r[i]);     pi[i] = lane_xor8(v1i[i]); }
                else if (s == 3) { pr[i] = lane_xor4(v1r[i]);     pi[i] = lane_xor4(v1i[i]); }
                else if (s == 4) { pr[i] = lane_xor2(v1r[i]);     pi[i] = lane_xor2(v1i[i]); }
                else             { pr[i] = lane_xor1(v1r[i]);     pi[i] = lane_xor1(v1i[i]); }
            }
#pragma unroll
            for (int i = 0; i < 16; ++i) {
                const float sr = fmaf(sgn, v1r[i], pr[i]);
                const float si = fmaf(sgn, v1i[i], pi[i]);
                v1r[i] = sr * tc - si * ts;
                v1i[i] = sr * ts + si * tc;
            }
        }
    }
    // now (lane l, reg i) holds X[k], k = BR4[i] + 16*brev6(l), per stream

    // ---- conjugate-symmetry unpack + magnitudes -> mag LDS (both streams)
    {
        float y0r[16], y0i[16], y1r[16], y1i[16];
        y0r[0] = __shfl(v0r[0], l2, 64);
        y0i[0] = __shfl(v0i[0], l2, 64);
        y1r[0] = __shfl(v1r[0], l2, 64);
        y1i[0] = __shfl(v1i[0], l2, 64);
#pragma unroll
        for (int i = 1; i < 16; ++i) {
            y0r[i] = lane_xor63(v0r[PARTNER[i]], l);
            y0i[i] = lane_xor63(v0i[PARTNER[i]], l);
            y1r[i] = lane_xor63(v1r[PARTNER[i]], l);
            y1i[i] = lane_xor63(v1i[PARTNER[i]], l);
        }
        const int row = 4 * w;
#pragma unroll
        for (int i = 0; i < 16; ++i) {
            const int k = BR4[i] + 16 * bl;
            if (k <= 512) {
                const int ka = k + (k >> 5);
                {
                    const float sa = v0r[i] + y0r[i], sb = v0i[i] - y0i[i];
                    const float ua = v0i[i] + y0i[i], ub = y0r[i] - v0r[i];
                    if (hasA0) mag[row + 0][ka] = 0.5f * fast_sqrtf(fmaf(sa, sa, sb * sb));
                    if (hasB0) mag[row + 1][ka] = 0.5f * fast_sqrtf(fmaf(ua, ua, ub * ub));
                }
                {
                    const float sa = v1r[i] + y1r[i], sb = v1i[i] - y1i[i];
                    const float ua = v1i[i] + y1i[i], ub = y1r[i] - v1r[i];
                    if (hasA1) mag[row + 2][ka] = 0.5f * fast_sqrtf(fmaf(sa, sa, sb * sb));
                    if (hasB1) mag[row + 3][ka] = 0.5f * fast_sqrtf(fmaf(ua, ua, ub * ub));
                }
            }
        }
    }

    __syncthreads();

    // ---- coalesced write-out: rows of 16 consecutive t per f
    if (t0 + TT <= T_C) {
#pragma unroll 4
        for (int e = tid; e < F_C * TT; e += 256) {
            const int f = e >> 4;
            const int tt = e & 15;
            out[((size_t)b * F_C + f) * T_C + t0 + tt] = mag[tt][f + (f >> 5)];
        }
    } else {
        for (int e = tid; e < F_C * TT; e += 256) {
            const int f = e >> 4;
            const int tt = e & 15;
            const int t = t0 + tt;
            if (t < T_C)
                out[((size_t)b * F_C + f) * T_C + t] = mag[tt][f + (f >> 5)];
        }
    }
}

extern "C" void kernel_launch(void* const* d_in, const int* in_sizes, int n_in,
                              void* d_out, int out_size, void* d_ws, size_t ws_size,
                              hipStream_t stream) {
    const float* x   = (const float*)d_in[0];
    const float* wl  = (const float*)d_in[1];
    const float* st  = (const float*)d_in[2];
    const float* wp  = (const float*)d_in[3];
    float* out = (float*)d_out;
    float* tap = (float*)d_ws;   // T_C*NN floats ~ 2.55 MB

    win_kernel<<<dim3(T_C), dim3(256), 0, stream>>>(wl, st, wp, tap);
    fftw_kernel<<<dim3(B_C * NTILE), dim3(256), 0, stream>>>(x, st, tap, out);
}

// Round 12
// 85.369 us; speedup vs baseline: 1.7111x; 1.3708x over previous
//
#include <hip/hip_runtime.h>
#include <math.h>

#define NN 1024
#define B_C 64
#define L_C 160000
#define T_C 622
#define F_C 513
#define TT 16
#define NTILE ((T_C + TT - 1) / TT)   // 39
#define WIN_MIN_C (1024.0f / 20.0f)
#define WIN_MAX_C 1024.0f
#define TWO_PI 6.28318530717958647692f

typedef unsigned uv2 __attribute__((ext_vector_type(2)));

__device__ __forceinline__ int brev6(int x) {
    return ((x & 1) << 5) | ((x & 2) << 3) | ((x & 4) << 1) |
           ((x & 8) >> 1) | ((x & 16) >> 3) | ((x & 32) >> 5);
}

// ---- lane-exchange helpers: VALU-rate (permlane/DPP) where possible ----
__device__ __forceinline__ float lane_xor32(float v, int l) {
#if __has_builtin(__builtin_amdgcn_permlane32_swap)
    uv2 r = __builtin_amdgcn_permlane32_swap(__float_as_uint(v), __float_as_uint(v),
                                             false, false);
    return __uint_as_float((l & 32) ? r.x : r.y);
#else
    return __shfl_xor(v, 32, 64);
#endif
}
__device__ __forceinline__ float lane_xor16(float v, int l) {
#if __has_builtin(__builtin_amdgcn_permlane16_swap)
    uv2 r = __builtin_amdgcn_permlane16_swap(__float_as_uint(v), __float_as_uint(v),
                                             false, false);
    return __uint_as_float((l & 16) ? r.x : r.y);
#else
    return __shfl_xor(v, 16, 64);
#endif
}
__device__ __forceinline__ float lane_xor8(float v) {   // row_ror:8 == xor8
    return __int_as_float(__builtin_amdgcn_update_dpp(
        __float_as_int(v), __float_as_int(v), 0x128, 0xF, 0xF, false));
}
__device__ __forceinline__ float lane_xor4(float v) {   // ds_swizzle xor4
    return __int_as_float(__builtin_amdgcn_ds_swizzle(__float_as_int(v), 0x101F));
}
__device__ __forceinline__ float lane_xor2(float v) {   // quad_perm [2,3,0,1]
    return __int_as_float(__builtin_amdgcn_update_dpp(
        __float_as_int(v), __float_as_int(v), 0x4E, 0xF, 0xF, false));
}
__device__ __forceinline__ float lane_xor1(float v) {   // quad_perm [1,0,3,2]
    return __int_as_float(__builtin_amdgcn_update_dpp(
        __float_as_int(v), __float_as_int(v), 0xB1, 0xF, 0xF, false));
}
__device__ __forceinline__ float lane_mirror16(float v) { // row_mirror == xor15
    return __int_as_float(__builtin_amdgcn_update_dpp(
        __float_as_int(v), __float_as_int(v), 0x140, 0xF, 0xF, false));
}
__device__ __forceinline__ float lane_xor63(float v, int l) {
    return lane_xor32(lane_xor16(lane_mirror16(v), l), l);  // 15^16^32 = 63
}
__device__ __forceinline__ float lane_exch(float v, int l, int s) {
    switch (s) {
        case 0:  return lane_xor32(v, l);
        case 1:  return lane_xor16(v, l);
        case 2:  return lane_xor8(v);
        case 3:  return lane_xor4(v);
        case 4:  return lane_xor2(v);
        default: return lane_xor1(v);
    }
}
__device__ __forceinline__ float fast_sqrtf(float x) {
#if __has_builtin(__builtin_amdgcn_sqrtf)
    return __builtin_amdgcn_sqrtf(x);
#else
    return sqrtf(x);
#endif
}

// ---------------- Kernel A: per-frame normalized Hann taps ----------------
__global__ __launch_bounds__(256) void win_kernel(
    const float* __restrict__ win_length,
    const float* __restrict__ strides,
    const float* __restrict__ win_pow,
    float* __restrict__ tap)   // [T_C][NN]
{
    const int t = blockIdx.x;
    const int tid = threadIdx.x;

    const float wl = fminf(fmaxf(win_length[0], WIN_MIN_C), WIN_MAX_C);
    const float st = fminf(fmaxf(strides[0], 0.0f), WIN_MAX_C);
    const float wp = win_pow[0];

    const float frame = (float)t * st;
    const float frac = frame - floorf(frame);

    const float hi = ceilf(((float)NN - 1.0f + wl) * 0.5f);
    const float lo = floorf(((float)NN - 1.0f - wl) * 0.5f);
    const float off = (wl - (float)NN + 1.0f) * 0.5f;
    const float inv_wl = 1.0f / wl;

    __shared__ float s_tap[NN];
    __shared__ float s_red[256];

    float local = 0.0f;
    for (int n = tid; n < NN; n += 256) {
        float base = (float)n - frac;
        float v = 0.5f - 0.5f * cosf(TWO_PI * (base + off) * inv_wl);
        if (base >= hi || base <= lo) v = 0.0f;
        s_tap[n] = v;
        local += v;
    }
    s_red[tid] = local;
    __syncthreads();
    for (int s = 128; s > 0; s >>= 1) {
        if (tid < s) s_red[tid] += s_red[tid + s];
        __syncthreads();
    }
    const float inv_sum = 1.0f / s_red[0];
    const bool pow_one = (wp == 1.0f);
    for (int n = tid; n < NN; n += 256) {
        float v = s_tap[n] * inv_sum;
        if (!pow_one) v = powf(v, wp);
        tap[t * NN + n] = v;
    }
}

// ---- 16-point DIF FFT over a register array (compile-time indices) ----
#define FFT16(vr, vi)                                                         \
    _Pragma("unroll")                                                         \
    for (int s = 0; s < 4; ++s) {                                             \
        const int half_ = (16 >> s) >> 1;                                     \
        _Pragma("unroll")                                                     \
        for (int b0 = 0; b0 < 16; b0 += (16 >> s)) {                          \
            _Pragma("unroll")                                                 \
            for (int j = 0; j < 8; ++j) {                                     \
                if (j < half_) {                                              \
                    const int i0 = b0 + j, i1 = b0 + j + half_;               \
                    const float ur = vr[i0], ui = vi[i0];                     \
                    const float wr = vr[i1], wi = vi[i1];                     \
                    vr[i0] = ur + wr; vi[i0] = ui + wi;                       \
                    const float dr = ur - wr, di = ui - wi;                   \
                    const float c = C16[j << s], ss = S16[j << s];            \
                    vr[i1] = dr * c - di * ss;                                \
                    vi[i1] = dr * ss + di * c;                                \
                }                                                             \
            }                                                                 \
        }                                                                     \
    }

// --- Kernel B: 4 waves/block, TWO packed FFTs (4 frames) per wave ---
// amdgpu_waves_per_eu(2,4): VGPR cap 128-256 -> fits ~95-live state, NO SPILL.
__global__ void __launch_bounds__(256)
__attribute__((amdgpu_waves_per_eu(2, 4)))
fftw_kernel(
    const float* __restrict__ x,        // [B_C][L_C]
    const float* __restrict__ strides,
    const float* __restrict__ tap,      // [T_C][NN]
    float* __restrict__ out)            // [B_C][F_C][T_C]
{
    const int tile = blockIdx.x % NTILE;
    const int b = blockIdx.x / NTILE;
    const int t0 = tile * TT;
    const int tid = threadIdx.x;
    const int w = tid >> 6;      // wave id 0..3 -> frame quad
    const int l = tid & 63;      // lane

    const float st = fminf(fmaxf(strides[0], 0.0f), WIN_MAX_C);
    const float* xb = x + (size_t)b * L_C;

    __shared__ float mag[TT][F_C + 16];   // 529-float rows: stride%32=17, coprime

    const int bl = brev6(l);
    const int l2 = brev6((64 - bl) & 63);   // unpack partner lane for k1==0 reg

    constexpr int BR4[16]     = {0,8,4,12,2,10,6,14,1,9,5,13,3,11,7,15};
    constexpr int PARTNER[16] = {0,1,3,2,7,6,5,4,15,14,13,12,11,10,9,8};
    constexpr float C16[8] = {1.0f, 0.92387953251f, 0.70710678119f, 0.38268343236f,
                              0.0f, -0.38268343236f, -0.70710678119f, -0.92387953251f};
    constexpr float S16[8] = {0.0f, -0.38268343236f, -0.70710678119f, -0.92387953251f,
                              -1.0f, -0.92387953251f, -0.70710678119f, -0.38268343236f};

    // stream 0: frames tA0 (re), tB0 (im); stream 1: frames tA1, tB1
    const int tA0 = t0 + 4 * w;
    const int tB0 = tA0 + 1, tA1 = tA0 + 2, tB1 = tA0 + 3;
    const bool hasA0 = (tA0 < T_C), hasB0 = (tB0 < T_C);
    const bool hasA1 = (tA1 < T_C), hasB1 = (tB1 < T_C);
    const int idxA0 = hasA0 ? (int)floorf((float)tA0 * st) : 0;
    const int idxB0 = hasB0 ? (int)floorf((float)tB0 * st) : 0;
    const int idxA1 = hasA1 ? (int)floorf((float)tA1 * st) : 0;
    const int idxB1 = hasB1 ? (int)floorf((float)tB1 * st) : 0;
    const float* tpA0 = tap + (size_t)tA0 * NN;
    const float* tpB0 = tap + (size_t)tB0 * NN;
    const float* tpA1 = tap + (size_t)tA1 * NN;
    const float* tpB1 = tap + (size_t)tB1 * NN;

    float v0r[16], v0i[16], v1r[16], v1i[16];

    // ---- load + taper; wave-uniform in-bounds fast path
    const bool ok = hasA0 && hasB0 && hasA1 && hasB1 &&
                    (idxA0 >= 0) && (idxB1 + NN <= L_C);
    if (ok) {
#pragma unroll
        for (int r = 0; r < 16; ++r) {
            const int n = r * 64 + l;
            v0r[r] = xb[idxA0 + n] * tpA0[n];
            v0i[r] = xb[idxB0 + n] * tpB0[n];
            v1r[r] = xb[idxA1 + n] * tpA1[n];
            v1i[r] = xb[idxB1 + n] * tpB1[n];
        }
    } else {
#pragma unroll
        for (int r = 0; r < 16; ++r) {
            const int n = r * 64 + l;
            float a0 = 0.0f, b0v = 0.0f, a1 = 0.0f, b1v = 0.0f;
            if (hasA0) { int i_ = idxA0 + n; a0  = (i_ >= 0 && i_ < L_C) ? xb[i_] * tpA0[n] : 0.0f; }
            if (hasB0) { int i_ = idxB0 + n; b0v = (i_ >= 0 && i_ < L_C) ? xb[i_] * tpB0[n] : 0.0f; }
            if (hasA1) { int i_ = idxA1 + n; a1  = (i_ >= 0 && i_ < L_C) ? xb[i_] * tpA1[n] : 0.0f; }
            if (hasB1) { int i_ = idxB1 + n; b1v = (i_ >= 0 && i_ < L_C) ? xb[i_] * tpB1[n] : 0.0f; }
            v0r[r] = a0; v0i[r] = b0v;
            v1r[r] = a1; v1i[r] = b1v;
        }
    }

    // ---- 16-point DIF FFT over registers, both streams
    FFT16(v0r, v0i)
    FFT16(v1r, v1i)

    // ---- twiddle W_1024^(l*k1): base powers {1,2,4,8,12}, rest applied
    //      as computed via angle add/sub -> peak ~10 live constants.
    {
        float c1, s1;
        __sincosf(-(TWO_PI / 1024.0f) * (float)l, &s1, &c1);
        const float c2 = c1 * c1 - s1 * s1,   s2 = 2.0f * c1 * s1;
        const float c4 = c2 * c2 - s2 * s2,   s4 = 2.0f * c2 * s2;
        const float c8 = c4 * c4 - s4 * s4,   s8 = 2.0f * c4 * s4;
        const float c12 = c8 * c4 - s8 * s4,  s12 = s8 * c4 + c8 * s4;
#define TW2(K, cc, ss) { const int i_ = BR4[K];                                \
                { const float ar = v0r[i_], ai = v0i[i_];                      \
                  v0r[i_] = ar * (cc) - ai * (ss);                             \
                  v0i[i_] = ar * (ss) + ai * (cc); }                           \
                { const float ar = v1r[i_], ai = v1i[i_];                      \
                  v1r[i_] = ar * (cc) - ai * (ss);                             \
                  v1i[i_] = ar * (ss) + ai * (cc); } }
        TW2(1, c1, s1)
        TW2(2, c2, s2)
        TW2(4, c4, s4)
        TW2(8, c8, s8)
        TW2(12, c12, s12)
        { const float cc = c4 * c1 + s4 * s1, ss = s4 * c1 - c4 * s1;   // 4-1
          TW2(3, cc, ss) }
        { const float cc = c4 * c1 - s4 * s1, ss = s4 * c1 + c4 * s1;   // 4+1
          TW2(5, cc, ss) }
        { const float cc = c8 * c2 + s8 * s2, ss = s8 * c2 - c8 * s2;   // 8-2
          TW2(6, cc, ss) }
        { const float cc = c8 * c1 + s8 * s1, ss = s8 * c1 - c8 * s1;   // 8-1
          TW2(7, cc, ss) }
        { const float cc = c8 * c1 - s8 * s1, ss = s8 * c1 + c8 * s1;   // 8+1
          TW2(9, cc, ss) }
        { const float cc = c8 * c2 - s8 * s2, ss = s8 * c2 + c8 * s2;   // 8+2
          TW2(10, cc, ss) }
        { const float cc = c12 * c1 + s12 * s1, ss = s12 * c1 - c12 * s1; // 12-1
          TW2(11, cc, ss) }
        { const float cc = c12 * c1 - s12 * s1, ss = s12 * c1 + c12 * s1; // 12+1
          TW2(13, cc, ss) }
        { const float cc = c12 * c2 - s12 * s2, ss = s12 * c2 + c12 * s2; // 12+2
          TW2(14, cc, ss) }
        { const float c3 = c4 * c1 + s4 * s1, s3 = s4 * c1 - c4 * s1;     // 12+3
          const float cc = c12 * c3 - s12 * s3, ss = s12 * c3 + c12 * s3;
          TW2(15, cc, ss) }
#undef TW2
    }

    // ---- 64-point DIF FFT across lanes; chunked exchanges (low liveness)
#pragma unroll
    for (int s = 0; s < 6; ++s) {
        const int half = 32 >> s;
        const bool low = (l & (2 * half - 1)) < half;
        const float sgn = low ? 1.0f : -1.0f;
        const int j = l & (half - 1);
        float sv, cv;
        __sincosf(-(TWO_PI * (float)j) / (float)(2 * half), &sv, &cv);
        const float tc = low ? 1.0f : cv;
        const float ts = low ? 0.0f : sv;
#pragma unroll
        for (int c0 = 0; c0 < 16; c0 += 4) {
            float pr[4], pi[4];
            // stream 0 chunk
#pragma unroll
            for (int q = 0; q < 4; ++q) {
                pr[q] = lane_exch(v0r[c0 + q], l, s);
                pi[q] = lane_exch(v0i[c0 + q], l, s);
            }
#pragma unroll
            for (int q = 0; q < 4; ++q) {
                const int i = c0 + q;
                const float sr = fmaf(sgn, v0r[i], pr[q]);
                const float si = fmaf(sgn, v0i[i], pi[q]);
                v0r[i] = sr * tc - si * ts;
                v0i[i] = sr * ts + si * tc;
            }
            // stream 1 chunk (reuses pr/pi)
#pragma unroll
            for (int q = 0; q < 4; ++q) {
                pr[q] = lane_exch(v1r[c0 + q], l, s);
                pi[q] = lane_exch(v1i[c0 + q], l, s);
            }
#pragma unroll
            for (int q = 0; q < 4; ++q) {
                const int i = c0 + q;
                const float sr = fmaf(sgn, v1r[i], pr[q]);
                const float si = fmaf(sgn, v1i[i], pi[q]);
                v1r[i] = sr * tc - si * ts;
                v1i[i] = sr * ts + si * tc;
            }
        }
    }
    // now (lane l, reg i) holds X[k], k = BR4[i] + 16*brev6(l), per stream

    // ---- conjugate-symmetry unpack + magnitudes, per-i (low liveness)
    {
        const int row = 4 * w;
        // i = 0 (k1 == 0): partner lives at lane l2, same reg
        {
            const float y0r = __shfl(v0r[0], l2, 64);
            const float y0i = __shfl(v0i[0], l2, 64);
            const float y1r = __shfl(v1r[0], l2, 64);
            const float y1i = __shfl(v1i[0], l2, 64);
            const int k = 16 * bl;
            if (k <= 512) {
                const int ka = k + (k >> 5);
                {
                    const float sa = v0r[0] + y0r, sb = v0i[0] - y0i;
                    const float ua = v0i[0] + y0i, ub = y0r - v0r[0];
                    if (hasA0) mag[row + 0][ka] = 0.5f * fast_sqrtf(fmaf(sa, sa, sb * sb));
                    if (hasB0) mag[row + 1][ka] = 0.5f * fast_sqrtf(fmaf(ua, ua, ub * ub));
                }
                {
                    const float sa = v1r[0] + y1r, sb = v1i[0] - y1i;
                    const float ua = v1i[0] + y1i, ub = y1r - v1r[0];
                    if (hasA1) mag[row + 2][ka] = 0.5f * fast_sqrtf(fmaf(sa, sa, sb * sb));
                    if (hasB1) mag[row + 3][ka] = 0.5f * fast_sqrtf(fmaf(ua, ua, ub * ub));
                }
            }
        }
#pragma unroll
        for (int i = 1; i < 16; ++i) {
            const float y0r = lane_xor63(v0r[PARTNER[i]], l);
            const float y0i = lane_xor63(v0i[PARTNER[i]], l);
            const float y1r = lane_xor63(v1r[PARTNER[i]], l);
            const float y1i = lane_xor63(v1i[PARTNER[i]], l);
            const int k = BR4[i] + 16 * bl;
            if (k <= 512) {
                const int ka = k + (k >> 5);
                {
                    const float sa = v0r[i] + y0r, sb = v0i[i] - y0i;
                    const float ua = v0i[i] + y0i, ub = y0r - v0r[i];
                    if (hasA0) mag[row + 0][ka] = 0.5f * fast_sqrtf(fmaf(sa, sa, sb * sb));
                    if (hasB0) mag[row + 1][ka] = 0.5f * fast_sqrtf(fmaf(ua, ua, ub * ub));
                }
                {
                    const float sa = v1r[i] + y1r, sb = v1i[i] - y1i;
                    const float ua = v1i[i] + y1i, ub = y1r - v1r[i];
                    if (hasA1) mag[row + 2][ka] = 0.5f * fast_sqrtf(fmaf(sa, sa, sb * sb));
                    if (hasB1) mag[row + 3][ka] = 0.5f * fast_sqrtf(fmaf(ua, ua, ub * ub));
                }
            }
        }
    }

    __syncthreads();

    // ---- coalesced write-out: rows of 16 consecutive t per f
    if (t0 + TT <= T_C) {
#pragma unroll 4
        for (int e = tid; e < F_C * TT; e += 256) {
            const int f = e >> 4;
            const int tt = e & 15;
            out[((size_t)b * F_C + f) * T_C + t0 + tt] = mag[tt][f + (f >> 5)];
        }
    } else {
        for (int e = tid; e < F_C * TT; e += 256) {
            const int f = e >> 4;
            const int tt = e & 15;
            const int t = t0 + tt;
            if (t < T_C)
                out[((size_t)b * F_C + f) * T_C + t] = mag[tt][f + (f >> 5)];
        }
    }
}

extern "C" void kernel_launch(void* const* d_in, const int* in_sizes, int n_in,
                              void* d_out, int out_size, void* d_ws, size_t ws_size,
                              hipStream_t stream) {
    const float* x   = (const float*)d_in[0];
    const float* wl  = (const float*)d_in[1];
    const float* st  = (const float*)d_in[2];
    const float* wp  = (const float*)d_in[3];
    float* out = (float*)d_out;
    float* tap = (float*)d_ws;   // T_C*NN floats ~ 2.55 MB

    win_kernel<<<dim3(T_C), dim3(256), 0, stream>>>(wl, st, wp, tap);
    fftw_kernel<<<dim3(B_C * NTILE), dim3(256), 0, stream>>>(x, st, tap, out);
}

// Round 13
// 76.397 us; speedup vs baseline: 1.9120x; 1.1174x over previous
//
#include <hip/hip_runtime.h>
#include <math.h>

#define NN 1024
#define B_C 64
#define L_C 160000
#define T_C 622
#define F_C 513
#define TT 16
#define NTILE ((T_C + TT - 1) / TT)   // 39
#define WIN_MIN_C (1024.0f / 20.0f)
#define WIN_MAX_C 1024.0f
#define TWO_PI 6.28318530717958647692f

typedef unsigned uv2 __attribute__((ext_vector_type(2)));

__device__ __forceinline__ int brev6(int x) {
    return ((x & 1) << 5) | ((x & 2) << 3) | ((x & 4) << 1) |
           ((x & 8) >> 1) | ((x & 16) >> 3) | ((x & 32) >> 5);
}

// ---- lane-exchange helpers ----
__device__ __forceinline__ float lane_xor32(float v, int l) {
#if __has_builtin(__builtin_amdgcn_permlane32_swap)
    uv2 r = __builtin_amdgcn_permlane32_swap(__float_as_uint(v), __float_as_uint(v),
                                             false, false);
    return __uint_as_float((l & 32) ? r.x : r.y);
#else
    return __shfl_xor(v, 32, 64);
#endif
}
__device__ __forceinline__ float lane_xor16(float v, int l) {
#if __has_builtin(__builtin_amdgcn_permlane16_swap)
    uv2 r = __builtin_amdgcn_permlane16_swap(__float_as_uint(v), __float_as_uint(v),
                                             false, false);
    return __uint_as_float((l & 16) ? r.x : r.y);
#else
    return __shfl_xor(v, 16, 64);
#endif
}
__device__ __forceinline__ float lane_xor8(float v) {   // row_ror:8 == xor8
    return __int_as_float(__builtin_amdgcn_update_dpp(
        __float_as_int(v), __float_as_int(v), 0x128, 0xF, 0xF, false));
}
__device__ __forceinline__ float lane_xor4(float v) {   // ds_swizzle xor4
    return __int_as_float(__builtin_amdgcn_ds_swizzle(__float_as_int(v), 0x101F));
}
__device__ __forceinline__ float lane_xor2(float v) {   // quad_perm [2,3,0,1]
    return __int_as_float(__builtin_amdgcn_update_dpp(
        __float_as_int(v), __float_as_int(v), 0x4E, 0xF, 0xF, false));
}
__device__ __forceinline__ float lane_xor1(float v) {   // quad_perm [1,0,3,2]
    return __int_as_float(__builtin_amdgcn_update_dpp(
        __float_as_int(v), __float_as_int(v), 0xB1, 0xF, 0xF, false));
}
__device__ __forceinline__ float lane_mirror16(float v) { // row_mirror == xor15
    return __int_as_float(__builtin_amdgcn_update_dpp(
        __float_as_int(v), __float_as_int(v), 0x140, 0xF, 0xF, false));
}
__device__ __forceinline__ float lane_xor63(float v, int l) {
    return lane_xor32(lane_xor16(lane_mirror16(v), l), l);  // 15^16^32 = 63
}
__device__ __forceinline__ float fast_sqrtf(float x) {
#if __has_builtin(__builtin_amdgcn_sqrtf)
    return __builtin_amdgcn_sqrtf(x);
#else
    return sqrtf(x);
#endif
}

// ---------------- Kernel A: per-frame normalized Hann taps ----------------
__global__ __launch_bounds__(256) void win_kernel(
    const float* __restrict__ win_length,
    const float* __restrict__ strides,
    const float* __restrict__ win_pow,
    float* __restrict__ tap)   // [T_C][NN]
{
    const int t = blockIdx.x;
    const int tid = threadIdx.x;

    const float wl = fminf(fmaxf(win_length[0], WIN_MIN_C), WIN_MAX_C);
    const float st = fminf(fmaxf(strides[0], 0.0f), WIN_MAX_C);
    const float wp = win_pow[0];

    const float frame = (float)t * st;
    const float frac = frame - floorf(frame);

    const float hi = ceilf(((float)NN - 1.0f + wl) * 0.5f);
    const float lo = floorf(((float)NN - 1.0f - wl) * 0.5f);
    const float off = (wl - (float)NN + 1.0f) * 0.5f;
    const float inv_wl = 1.0f / wl;

    __shared__ float s_tap[NN];
    __shared__ float s_red[256];

    float local = 0.0f;
    for (int n = tid; n < NN; n += 256) {
        float base = (float)n - frac;
        float v = 0.5f - 0.5f * cosf(TWO_PI * (base + off) * inv_wl);
        if (base >= hi || base <= lo) v = 0.0f;
        s_tap[n] = v;
        local += v;
    }
    s_red[tid] = local;
    __syncthreads();
    for (int s = 128; s > 0; s >>= 1) {
        if (tid < s) s_red[tid] += s_red[tid + s];
        __syncthreads();
    }
    const float inv_sum = 1.0f / s_red[0];
    const bool pow_one = (wp == 1.0f);
    for (int n = tid; n < NN; n += 256) {
        float v = s_tap[n] * inv_sum;
        if (!pow_one) v = powf(v, wp);
        tap[t * NN + n] = v;
    }
}

// --- Kernel B: 8 waves/block, wave-per-packed-FFT, fold-twiddle lane FFT ---
__global__ __launch_bounds__(512, 4) void fftw_kernel(
    const float* __restrict__ x,        // [B_C][L_C]
    const float* __restrict__ strides,
    const float* __restrict__ tap,      // [T_C][NN]
    float* __restrict__ out)            // [B_C][F_C][T_C]
{
    const int tile = blockIdx.x % NTILE;
    const int b = blockIdx.x / NTILE;
    const int t0 = tile * TT;
    const int tid = threadIdx.x;
    const int w = tid >> 6;      // wave id 0..7 = frame pair
    const int l = tid & 63;      // lane

    const float st = fminf(fmaxf(strides[0], 0.0f), WIN_MAX_C);
    const float* xb = x + (size_t)b * L_C;

    __shared__ float mag[TT][F_C + 16];   // 529-float rows: stride%32=17, coprime

    const int bl = brev6(l);
    const int l2 = brev6((64 - bl) & 63);   // unpack partner lane for k1==0 reg

    constexpr int BR4[16]     = {0,8,4,12,2,10,6,14,1,9,5,13,3,11,7,15};
    constexpr int PARTNER[16] = {0,1,3,2,7,6,5,4,15,14,13,12,11,10,9,8};
    constexpr float C16[8] = {1.0f, 0.92387953251f, 0.70710678119f, 0.38268343236f,
                              0.0f, -0.38268343236f, -0.70710678119f, -0.92387953251f};
    constexpr float S16[8] = {0.0f, -0.38268343236f, -0.70710678119f, -0.92387953251f,
                              -1.0f, -0.92387953251f, -0.70710678119f, -0.38268343236f};

    const int jp = w;                   // pair index 0..7
    const int tA = t0 + 2 * jp;
    const int tB = tA + 1;
    const bool hasA = (tA < T_C);
    const bool hasB = (tB < T_C);
    const int idxA = hasA ? (int)floorf((float)tA * st) : 0;
    const int idxB = hasB ? (int)floorf((float)tB * st) : 0;
    const float* tpA = tap + (size_t)tA * NN;
    const float* tpB = tap + (size_t)tB * NN;

    float vr[16], vi[16];

    // ---- load + taper: frame A -> re, frame B -> im; element n = 64*r + l
    const bool okA = hasA && (idxA >= 0) && (idxA + NN <= L_C);
    const bool okB = hasB && (idxB >= 0) && (idxB + NN <= L_C);
    if (okA && okB) {
#pragma unroll
        for (int r = 0; r < 16; ++r) {
            const int n = r * 64 + l;
            vr[r] = xb[idxA + n] * tpA[n];
            vi[r] = xb[idxB + n] * tpB[n];
        }
    } else {
#pragma unroll
        for (int r = 0; r < 16; ++r) {
            const int n = r * 64 + l;
            float a = 0.0f, bb = 0.0f;
            if (hasA) {
                int ia = idxA + n;
                a = (ia >= 0 && ia < L_C) ? xb[ia] * tpA[n] : 0.0f;
            }
            if (hasB) {
                int ib = idxB + n;
                bb = (ib >= 0 && ib < L_C) ? xb[ib] * tpB[n] : 0.0f;
            }
            vr[r] = a;
            vi[r] = bb;
        }
    }

    // ---- 16-point DIF FFT over registers (output i holds k1 = BR4[i])
#pragma unroll
    for (int s = 0; s < 4; ++s) {
        const int half = (16 >> s) >> 1;
#pragma unroll
        for (int b0 = 0; b0 < 16; b0 += (16 >> s)) {
#pragma unroll
            for (int j = 0; j < 8; ++j) {
                if (j < half) {
                    const int i0 = b0 + j, i1 = b0 + j + half;
                    const float ur = vr[i0], ui = vi[i0];
                    const float wr = vr[i1], wi = vi[i1];
                    vr[i0] = ur + wr; vi[i0] = ui + wi;
                    const float dr = ur - wr, di = ui - wi;
                    const float c = C16[j << s], ss = S16[j << s];
                    vr[i1] = dr * c - di * ss;
                    vi[i1] = dr * ss + di * c;
                }
            }
        }
    }

    // ---- twiddle W_1024^(l * k1): powers via doubling tree (log-depth, ILP)
    {
        float c1, s1;
        __sincosf(-(TWO_PI / 1024.0f) * (float)l, &s1, &c1);
        const float c2 = c1 * c1 - s1 * s1,  s2 = 2.0f * c1 * s1;
        const float c4 = c2 * c2 - s2 * s2,  s4 = 2.0f * c2 * s2;
        const float c8 = c4 * c4 - s4 * s4,  s8 = 2.0f * c4 * s4;
        const float c3 = c1 * c2 - s1 * s2,  s3 = c1 * s2 + s1 * c2;
        const float c5 = c1 * c4 - s1 * s4,  s5 = c1 * s4 + s1 * c4;
        const float c6 = c2 * c4 - s2 * s4,  s6 = c2 * s4 + s2 * c4;
        const float c7 = c3 * c4 - s3 * s4,  s7 = c3 * s4 + s3 * c4;
        const float c9  = c1 * c8 - s1 * s8, s9  = c1 * s8 + s1 * c8;
        const float c10 = c2 * c8 - s2 * s8, s10 = c2 * s8 + s2 * c8;
        const float c11 = c3 * c8 - s3 * s8, s11 = c3 * s8 + s3 * c8;
        const float c12 = c4 * c8 - s4 * s8, s12 = c4 * s8 + s4 * c8;
        const float c13 = c5 * c8 - s5 * s8, s13 = c5 * s8 + s5 * c8;
        const float c14 = c6 * c8 - s6 * s8, s14 = c6 * s8 + s6 * c8;
        const float c15 = c7 * c8 - s7 * s8, s15 = c7 * s8 + s7 * c8;
#define TW(K) { const int i_ = BR4[K]; const float ar = vr[i_], ai = vi[i_]; \
                vr[i_] = ar * c##K - ai * s##K; vi[i_] = ar * s##K + ai * c##K; }
        TW(1) TW(2) TW(3) TW(4) TW(5) TW(6) TW(7) TW(8)
        TW(9) TW(10) TW(11) TW(12) TW(13) TW(14) TW(15)
#undef TW
    }

    // ---- 64-point DIF FFT across lanes, fold-twiddle convention:
    //      d = v + sgn*p (high lanes: v - p), twiddle angle -2*pi*l*2^s/64
    //      (one sincos, doubled per stage). Identical outputs to standard.
    {
        float cu, su;
        __sincosf(-(TWO_PI / 64.0f) * (float)l, &su, &cu);

        // --- stage 0: xor32 via permlane32_swap both-halves ---
        {
            const bool hi_ = (l & 32) != 0;
            const float sgn = hi_ ? -1.0f : 1.0f;
            const float tc = hi_ ? cu : 1.0f;
            const float ts = hi_ ? su : 0.0f;
            float dr[16], di[16];
#pragma unroll
            for (int i = 0; i < 16; ++i) {
#if __has_builtin(__builtin_amdgcn_permlane32_swap)
                uv2 xr = __builtin_amdgcn_permlane32_swap(
                    __float_as_uint(vr[i]), __float_as_uint(vr[i]), false, false);
                uv2 xi = __builtin_amdgcn_permlane32_swap(
                    __float_as_uint(vi[i]), __float_as_uint(vi[i]), false, false);
                // xr.x = low-half value, xr.y = high-half value (both lanes)
                dr[i] = fmaf(sgn, __uint_as_float(xr.x), __uint_as_float(xr.y));
                di[i] = fmaf(sgn, __uint_as_float(xi.x), __uint_as_float(xi.y));
#else
                dr[i] = fmaf(sgn, __shfl_xor(vr[i], 32, 64), vr[i]);
                di[i] = fmaf(sgn, __shfl_xor(vi[i], 32, 64), vi[i]);
#endif
            }
#pragma unroll
            for (int i = 0; i < 16; ++i) {
                vr[i] = dr[i] * tc - di[i] * ts;
                vi[i] = dr[i] * ts + di[i] * tc;
            }
            const float nc = fmaf(2.0f * cu, cu, -1.0f);
            su = 2.0f * cu * su; cu = nc;
        }
        // --- stage 1: xor16 via permlane16_swap both-halves ---
        {
            const bool hi_ = (l & 16) != 0;
            const float sgn = hi_ ? -1.0f : 1.0f;
            const float tc = hi_ ? cu : 1.0f;
            const float ts = hi_ ? su : 0.0f;
            float dr[16], di[16];
#pragma unroll
            for (int i = 0; i < 16; ++i) {
#if __has_builtin(__builtin_amdgcn_permlane16_swap)
                uv2 xr = __builtin_amdgcn_permlane16_swap(
                    __float_as_uint(vr[i]), __float_as_uint(vr[i]), false, false);
                uv2 xi = __builtin_amdgcn_permlane16_swap(
                    __float_as_uint(vi[i]), __float_as_uint(vi[i]), false, false);
                dr[i] = fmaf(sgn, __uint_as_float(xr.x), __uint_as_float(xr.y));
                di[i] = fmaf(sgn, __uint_as_float(xi.x), __uint_as_float(xi.y));
#else
                dr[i] = fmaf(sgn, __shfl_xor(vr[i], 16, 64), vr[i]);
                di[i] = fmaf(sgn, __shfl_xor(vi[i], 16, 64), vi[i]);
#endif
            }
#pragma unroll
            for (int i = 0; i < 16; ++i) {
                vr[i] = dr[i] * tc - di[i] * ts;
                vi[i] = dr[i] * ts + di[i] * tc;
            }
            const float nc = fmaf(2.0f * cu, cu, -1.0f);
            su = 2.0f * cu * su; cu = nc;
        }
        // --- stages 2..4: xor8 (DPP), xor4 (swizzle), xor2 (DPP) ---
#define FOLD_STAGE(MASK, EXCH)                                                \
        {                                                                     \
            const bool hi_ = (l & (MASK)) != 0;                               \
            const float sgn = hi_ ? -1.0f : 1.0f;                             \
            const float tc = hi_ ? cu : 1.0f;                                 \
            const float ts = hi_ ? su : 0.0f;                                 \
            float dr[16], di[16];                                             \
            _Pragma("unroll")                                                 \
            for (int i = 0; i < 16; ++i) {                                    \
                dr[i] = fmaf(sgn, EXCH(vr[i]), vr[i]);                        \
                di[i] = fmaf(sgn, EXCH(vi[i]), vi[i]);                        \
            }                                                                 \
            _Pragma("unroll")                                                 \
            for (int i = 0; i < 16; ++i) {                                    \
                vr[i] = dr[i] * tc - di[i] * ts;                              \
                vi[i] = dr[i] * ts + di[i] * tc;                              \
            }                                                                 \
            const float nc = fmaf(2.0f * cu, cu, -1.0f);                      \
            su = 2.0f * cu * su; cu = nc;                                     \
        }
        FOLD_STAGE(8, lane_xor8)
        FOLD_STAGE(4, lane_xor4)
        FOLD_STAGE(2, lane_xor2)
#undef FOLD_STAGE
        // --- stage 5: xor1, twiddle == 1 -> plain butterfly (standard conv:
        //     out = p + sgn*v; low: p+v, high: p-v) ---
        {
            const float sgn = (l & 1) ? -1.0f : 1.0f;
#pragma unroll
            for (int i = 0; i < 16; ++i) {
                vr[i] = fmaf(sgn, vr[i], lane_xor1(vr[i]));
                vi[i] = fmaf(sgn, vi[i], lane_xor1(vi[i]));
            }
        }
    }
    // now (lane l, reg i) holds X[k], k = BR4[i] + 16*brev6(l)

    // ---- conjugate-symmetry unpack: batched exchanges, then magnitudes
    {
        float yr[16], yi[16];
        yr[0] = __shfl(vr[0], l2, 64);
        yi[0] = __shfl(vi[0], l2, 64);
#pragma unroll
        for (int i = 1; i < 16; ++i) {
            yr[i] = lane_xor63(vr[PARTNER[i]], l);
            yi[i] = lane_xor63(vi[PARTNER[i]], l);
        }
#pragma unroll
        for (int i = 0; i < 16; ++i) {
            const int k = BR4[i] + 16 * bl;
            if (k <= 512) {
                const float sa = vr[i] + yr[i], sb = vi[i] - yi[i]; // 2*A
                const float ua = vi[i] + yi[i], ub = yr[i] - vr[i]; // 2*B
                const int ka = k + (k >> 5);
                if (hasA) mag[2 * jp][ka] = 0.5f * fast_sqrtf(fmaf(sa, sa, sb * sb));
                if (hasB) mag[2 * jp + 1][ka] = 0.5f * fast_sqrtf(fmaf(ua, ua, ub * ub));
            }
        }
    }

    __syncthreads();

    // ---- coalesced write-out: float2 along t (622 % 4 == 2 -> 8B aligned)
    if (t0 + TT <= T_C) {
        for (int q = tid; q < F_C * 8; q += 512) {
            const int f = q >> 3;
            const int tg = (q & 7) << 1;
            const int fa = f + (f >> 5);
            float2 o;
            o.x = mag[tg + 0][fa];
            o.y = mag[tg + 1][fa];
            *(float2*)&out[((size_t)b * F_C + f) * T_C + t0 + tg] = o;
        }
    } else {
        for (int e = tid; e < F_C * TT; e += 512) {
            const int f = e >> 4;
            const int tt = e & 15;
            const int t = t0 + tt;
            if (t < T_C)
                out[((size_t)b * F_C + f) * T_C + t] = mag[tt][f + (f >> 5)];
        }
    }
}

extern "C" void kernel_launch(void* const* d_in, const int* in_sizes, int n_in,
                              void* d_out, int out_size, void* d_ws, size_t ws_size,
                              hipStream_t stream) {
    const float* x   = (const float*)d_in[0];
    const float* wl  = (const float*)d_in[1];
    const float* st  = (const float*)d_in[2];
    const float* wp  = (const float*)d_in[3];
    float* out = (float*)d_out;
    float* tap = (float*)d_ws;   // T_C*NN floats ~ 2.55 MB

    win_kernel<<<dim3(T_C), dim3(256), 0, stream>>>(wl, st, wp, tap);
    fftw_kernel<<<dim3(B_C * NTILE), dim3(512), 0, stream>>>(x, st, tap, out);
}

// Round 14
// 76.149 us; speedup vs baseline: 1.9182x; 1.0033x over previous
//
#include <hip/hip_runtime.h>
#include <math.h>

#define NN 1024
#define B_C 64
#define L_C 160000
#define T_C 622
#define F_C 513
#define TT 8
#define NTILE ((T_C + TT - 1) / TT)   // 78
#define WIN_MIN_C (1024.0f / 20.0f)
#define WIN_MAX_C 1024.0f
#define TWO_PI 6.28318530717958647692f

typedef unsigned uv2 __attribute__((ext_vector_type(2)));

__device__ __forceinline__ int brev6(int x) {
    return ((x & 1) << 5) | ((x & 2) << 3) | ((x & 4) << 1) |
           ((x & 8) >> 1) | ((x & 16) >> 3) | ((x & 32) >> 5);
}

// ---- lane-exchange helpers ----
__device__ __forceinline__ float lane_xor32(float v, int l) {
#if __has_builtin(__builtin_amdgcn_permlane32_swap)
    uv2 r = __builtin_amdgcn_permlane32_swap(__float_as_uint(v), __float_as_uint(v),
                                             false, false);
    return __uint_as_float((l & 32) ? r.x : r.y);
#else
    return __shfl_xor(v, 32, 64);
#endif
}
__device__ __forceinline__ float lane_xor8(float v) {   // row_ror:8 == xor8
    return __int_as_float(__builtin_amdgcn_update_dpp(
        __float_as_int(v), __float_as_int(v), 0x128, 0xF, 0xF, false));
}
__device__ __forceinline__ float lane_xor4(float v) {   // ds_swizzle xor4
    return __int_as_float(__builtin_amdgcn_ds_swizzle(__float_as_int(v), 0x101F));
}
__device__ __forceinline__ float lane_xor2(float v) {   // quad_perm [2,3,0,1]
    return __int_as_float(__builtin_amdgcn_update_dpp(
        __float_as_int(v), __float_as_int(v), 0x4E, 0xF, 0xF, false));
}
__device__ __forceinline__ float lane_xor1(float v) {   // quad_perm [1,0,3,2]
    return __int_as_float(__builtin_amdgcn_update_dpp(
        __float_as_int(v), __float_as_int(v), 0xB1, 0xF, 0xF, false));
}
__device__ __forceinline__ float lane_xor31(float v) {  // ds_swizzle xor31
    return __int_as_float(__builtin_amdgcn_ds_swizzle(__float_as_int(v), 0x7C1F));
}
__device__ __forceinline__ float lane_xor63(float v, int l) {
    return lane_xor32(lane_xor31(v), l);   // 31 ^ 32 = 63, 2 ops
}
__device__ __forceinline__ float fast_sqrtf(float x) {
#if __has_builtin(__builtin_amdgcn_sqrtf)
    return __builtin_amdgcn_sqrtf(x);
#else
    return sqrtf(x);
#endif
}

// ---------------- Kernel A: per-frame normalized Hann taps ----------------
__global__ __launch_bounds__(256) void win_kernel(
    const float* __restrict__ win_length,
    const float* __restrict__ strides,
    const float* __restrict__ win_pow,
    float* __restrict__ tap)   // [T_C][NN]
{
    const int t = blockIdx.x;
    const int tid = threadIdx.x;

    const float wl = fminf(fmaxf(win_length[0], WIN_MIN_C), WIN_MAX_C);
    const float st = fminf(fmaxf(strides[0], 0.0f), WIN_MAX_C);
    const float wp = win_pow[0];

    const float frame = (float)t * st;
    const float frac = frame - floorf(frame);

    const float hi = ceilf(((float)NN - 1.0f + wl) * 0.5f);
    const float lo = floorf(((float)NN - 1.0f - wl) * 0.5f);
    const float off = (wl - (float)NN + 1.0f) * 0.5f;
    const float inv_wl = 1.0f / wl;

    __shared__ float s_tap[NN];
    __shared__ float s_red[256];

    float local = 0.0f;
    for (int n = tid; n < NN; n += 256) {
        float base = (float)n - frac;
        float v = 0.5f - 0.5f * cosf(TWO_PI * (base + off) * inv_wl);
        if (base >= hi || base <= lo) v = 0.0f;
        s_tap[n] = v;
        local += v;
    }
    s_red[tid] = local;
    __syncthreads();
    for (int s = 128; s > 0; s >>= 1) {
        if (tid < s) s_red[tid] += s_red[tid + s];
        __syncthreads();
    }
    const float inv_sum = 1.0f / s_red[0];
    const bool pow_one = (wp == 1.0f);
    for (int n = tid; n < NN; n += 256) {
        float v = s_tap[n] * inv_sum;
        if (!pow_one) v = powf(v, wp);
        tap[t * NN + n] = v;
    }
}

// --- Kernel B: 4 waves/block (TT=8), wave-per-packed-FFT, fold twiddles ---
__global__ __launch_bounds__(256, 4) void fftw_kernel(
    const float* __restrict__ x,        // [B_C][L_C]
    const float* __restrict__ strides,
    const float* __restrict__ tap,      // [T_C][NN]
    float* __restrict__ out)            // [B_C][F_C][T_C]
{
    const int tile = blockIdx.x % NTILE;
    const int b = blockIdx.x / NTILE;
    const int t0 = tile * TT;
    const int tid = threadIdx.x;
    const int w = tid >> 6;      // wave id 0..3 = frame pair
    const int l = tid & 63;      // lane

    const float st = fminf(fmaxf(strides[0], 0.0f), WIN_MAX_C);
    const float* xb = x + (size_t)b * L_C;

    __shared__ float mag[TT][F_C + 16];   // 529-float rows: stride%32=17, coprime

    const int bl = brev6(l);
    const int l2 = brev6((64 - bl) & 63);   // unpack partner lane for k1==0 reg

    constexpr int BR4[16]     = {0,8,4,12,2,10,6,14,1,9,5,13,3,11,7,15};
    constexpr int PARTNER[16] = {0,1,3,2,7,6,5,4,15,14,13,12,11,10,9,8};
    constexpr float C16[8] = {1.0f, 0.92387953251f, 0.70710678119f, 0.38268343236f,
                              0.0f, -0.38268343236f, -0.70710678119f, -0.92387953251f};
    constexpr float S16[8] = {0.0f, -0.38268343236f, -0.70710678119f, -0.92387953251f,
                              -1.0f, -0.92387953251f, -0.70710678119f, -0.38268343236f};

    const int jp = w;                   // pair index 0..3
    const int tA = t0 + 2 * jp;
    const int tB = tA + 1;
    const bool hasA = (tA < T_C);
    const bool hasB = (tB < T_C);
    const int idxA = hasA ? (int)floorf((float)tA * st) : 0;
    const int idxB = hasB ? (int)floorf((float)tB * st) : 0;
    const float* tpA = tap + (size_t)tA * NN;
    const float* tpB = tap + (size_t)tB * NN;

    float vr[16], vi[16];

    // ---- load + taper: frame A -> re, frame B -> im; element n = 64*r + l
    const bool okA = hasA && (idxA >= 0) && (idxA + NN <= L_C);
    const bool okB = hasB && (idxB >= 0) && (idxB + NN <= L_C);
    if (okA && okB) {
#pragma unroll
        for (int r = 0; r < 16; ++r) {
            const int n = r * 64 + l;
            vr[r] = xb[idxA + n] * tpA[n];
            vi[r] = xb[idxB + n] * tpB[n];
        }
    } else {
#pragma unroll
        for (int r = 0; r < 16; ++r) {
            const int n = r * 64 + l;
            float a = 0.0f, bb = 0.0f;
            if (hasA) {
                int ia = idxA + n;
                a = (ia >= 0 && ia < L_C) ? xb[ia] * tpA[n] : 0.0f;
            }
            if (hasB) {
                int ib = idxB + n;
                bb = (ib >= 0 && ib < L_C) ? xb[ib] * tpB[n] : 0.0f;
            }
            vr[r] = a;
            vi[r] = bb;
        }
    }

    // ---- 16-point DIF FFT over registers (output i holds k1 = BR4[i])
#pragma unroll
    for (int s = 0; s < 4; ++s) {
        const int half = (16 >> s) >> 1;
#pragma unroll
        for (int b0 = 0; b0 < 16; b0 += (16 >> s)) {
#pragma unroll
            for (int j = 0; j < 8; ++j) {
                if (j < half) {
                    const int i0 = b0 + j, i1 = b0 + j + half;
                    const float ur = vr[i0], ui = vi[i0];
                    const float wr = vr[i1], wi = vi[i1];
                    vr[i0] = ur + wr; vi[i0] = ui + wi;
                    const float dr = ur - wr, di = ui - wi;
                    const float c = C16[j << s], ss = S16[j << s];
                    vr[i1] = dr * c - di * ss;
                    vi[i1] = dr * ss + di * c;
                }
            }
        }
    }

    // ---- twiddle W_1024^(l * k1): powers via doubling tree (log-depth, ILP)
    {
        float c1, s1;
        __sincosf(-(TWO_PI / 1024.0f) * (float)l, &s1, &c1);
        const float c2 = c1 * c1 - s1 * s1,  s2 = 2.0f * c1 * s1;
        const float c4 = c2 * c2 - s2 * s2,  s4 = 2.0f * c2 * s2;
        const float c8 = c4 * c4 - s4 * s4,  s8 = 2.0f * c4 * s4;
        const float c3 = c1 * c2 - s1 * s2,  s3 = c1 * s2 + s1 * c2;
        const float c5 = c1 * c4 - s1 * s4,  s5 = c1 * s4 + s1 * c4;
        const float c6 = c2 * c4 - s2 * s4,  s6 = c2 * s4 + s2 * c4;
        const float c7 = c3 * c4 - s3 * s4,  s7 = c3 * s4 + s3 * c4;
        const float c9  = c1 * c8 - s1 * s8, s9  = c1 * s8 + s1 * c8;
        const float c10 = c2 * c8 - s2 * s8, s10 = c2 * s8 + s2 * c8;
        const float c11 = c3 * c8 - s3 * s8, s11 = c3 * s8 + s3 * c8;
        const float c12 = c4 * c8 - s4 * s8, s12 = c4 * s8 + s4 * c8;
        const float c13 = c5 * c8 - s5 * s8, s13 = c5 * s8 + s5 * c8;
        const float c14 = c6 * c8 - s6 * s8, s14 = c6 * s8 + s6 * c8;
        const float c15 = c7 * c8 - s7 * s8, s15 = c7 * s8 + s7 * c8;
#define TW(K) { const int i_ = BR4[K]; const float ar = vr[i_], ai = vi[i_]; \
                vr[i_] = ar * c##K - ai * s##K; vi[i_] = ar * s##K + ai * c##K; }
        TW(1) TW(2) TW(3) TW(4) TW(5) TW(6) TW(7) TW(8)
        TW(9) TW(10) TW(11) TW(12) TW(13) TW(14) TW(15)
#undef TW
    }

    // ---- 64-point DIF FFT across lanes, fold-twiddle convention:
    //      d = v + sgn*p (high: v - p), angle -2*pi*l*2^s/64, 1 sincos total.
    {
        float cu, su;
        __sincosf(-(TWO_PI / 64.0f) * (float)l, &su, &cu);

        // --- stage 0: xor32 via permlane32_swap both-halves ---
        {
            const bool hi_ = (l & 32) != 0;
            const float sgn = hi_ ? -1.0f : 1.0f;
            const float tc = hi_ ? cu : 1.0f;
            const float ts = hi_ ? su : 0.0f;
            float dr[16], di[16];
#pragma unroll
            for (int i = 0; i < 16; ++i) {
#if __has_builtin(__builtin_amdgcn_permlane32_swap)
                uv2 xr = __builtin_amdgcn_permlane32_swap(
                    __float_as_uint(vr[i]), __float_as_uint(vr[i]), false, false);
                uv2 xi = __builtin_amdgcn_permlane32_swap(
                    __float_as_uint(vi[i]), __float_as_uint(vi[i]), false, false);
                dr[i] = fmaf(sgn, __uint_as_float(xr.x), __uint_as_float(xr.y));
                di[i] = fmaf(sgn, __uint_as_float(xi.x), __uint_as_float(xi.y));
#else
                dr[i] = fmaf(sgn, __shfl_xor(vr[i], 32, 64), vr[i]);
                di[i] = fmaf(sgn, __shfl_xor(vi[i], 32, 64), vi[i]);
#endif
            }
#pragma unroll
            for (int i = 0; i < 16; ++i) {
                vr[i] = dr[i] * tc - di[i] * ts;
                vi[i] = dr[i] * ts + di[i] * tc;
            }
            const float nc = fmaf(2.0f * cu, cu, -1.0f);
            su = 2.0f * cu * su; cu = nc;
        }
        // --- stage 1: xor16 via permlane16_swap both-halves ---
        {
            const bool hi_ = (l & 16) != 0;
            const float sgn = hi_ ? -1.0f : 1.0f;
            const float tc = hi_ ? cu : 1.0f;
            const float ts = hi_ ? su : 0.0f;
            float dr[16], di[16];
#pragma unroll
            for (int i = 0; i < 16; ++i) {
#if __has_builtin(__builtin_amdgcn_permlane16_swap)
                uv2 xr = __builtin_amdgcn_permlane16_swap(
                    __float_as_uint(vr[i]), __float_as_uint(vr[i]), false, false);
                uv2 xi = __builtin_amdgcn_permlane16_swap(
                    __float_as_uint(vi[i]), __float_as_uint(vi[i]), false, false);
                dr[i] = fmaf(sgn, __uint_as_float(xr.x), __uint_as_float(xr.y));
                di[i] = fmaf(sgn, __uint_as_float(xi.x), __uint_as_float(xi.y));
#else
                dr[i] = fmaf(sgn, __shfl_xor(vr[i], 16, 64), vr[i]);
                di[i] = fmaf(sgn, __shfl_xor(vi[i], 16, 64), vi[i]);
#endif
            }
#pragma unroll
            for (int i = 0; i < 16; ++i) {
                vr[i] = dr[i] * tc - di[i] * ts;
                vi[i] = dr[i] * ts + di[i] * tc;
            }
            const float nc = fmaf(2.0f * cu, cu, -1.0f);
            su = 2.0f * cu * su; cu = nc;
        }
        // --- stages 2..4: xor8 (DPP), xor4 (swizzle), xor2 (DPP) ---
#define FOLD_STAGE(MASK, EXCH)                                                \
        {                                                                     \
            const bool hi_ = (l & (MASK)) != 0;                               \
            const float sgn = hi_ ? -1.0f : 1.0f;                             \
            const float tc = hi_ ? cu : 1.0f;                                 \
            const float ts = hi_ ? su : 0.0f;                                 \
            float dr[16], di[16];                                             \
            _Pragma("unroll")                                                 \
            for (int i = 0; i < 16; ++i) {                                    \
                dr[i] = fmaf(sgn, EXCH(vr[i]), vr[i]);                        \
                di[i] = fmaf(sgn, EXCH(vi[i]), vi[i]);                        \
            }                                                                 \
            _Pragma("unroll")                                                 \
            for (int i = 0; i < 16; ++i) {                                    \
                vr[i] = dr[i] * tc - di[i] * ts;                              \
                vi[i] = dr[i] * ts + di[i] * tc;                              \
            }                                                                 \
            const float nc = fmaf(2.0f * cu, cu, -1.0f);                      \
            su = 2.0f * cu * su; cu = nc;                                     \
        }
        FOLD_STAGE(8, lane_xor8)
        FOLD_STAGE(4, lane_xor4)
        FOLD_STAGE(2, lane_xor2)
#undef FOLD_STAGE
        // --- stage 5: xor1, twiddle == 1 -> plain butterfly ---
        {
            const float sgn = (l & 1) ? -1.0f : 1.0f;
#pragma unroll
            for (int i = 0; i < 16; ++i) {
                vr[i] = fmaf(sgn, vr[i], lane_xor1(vr[i]));
                vi[i] = fmaf(sgn, vi[i], lane_xor1(vi[i]));
            }
        }
    }
    // now (lane l, reg i) holds X[k], k = BR4[i] + 16*brev6(l)

    // ---- conjugate-symmetry unpack: batched exchanges, then magnitudes
    {
        float yr[16], yi[16];
        yr[0] = __shfl(vr[0], l2, 64);
        yi[0] = __shfl(vi[0], l2, 64);
#pragma unroll
        for (int i = 1; i < 16; ++i) {
            yr[i] = lane_xor63(vr[PARTNER[i]], l);
            yi[i] = lane_xor63(vi[PARTNER[i]], l);
        }
#pragma unroll
        for (int i = 0; i < 16; ++i) {
            const int k = BR4[i] + 16 * bl;
            if (k <= 512) {
                const float sa = vr[i] + yr[i], sb = vi[i] - yi[i]; // 2*A
                const float ua = vi[i] + yi[i], ub = yr[i] - vr[i]; // 2*B
                const int ka = k + (k >> 5);
                if (hasA) mag[2 * jp][ka] = 0.5f * fast_sqrtf(fmaf(sa, sa, sb * sb));
                if (hasB) mag[2 * jp + 1][ka] = 0.5f * fast_sqrtf(fmaf(ua, ua, ub * ub));
            }
        }
    }

    __syncthreads();

    // ---- coalesced write-out: float2 along t (622 even -> 8B aligned)
    if (t0 + TT <= T_C) {
        for (int q = tid; q < F_C * (TT / 2); q += 256) {
            const int f = q >> 2;
            const int tg = (q & 3) << 1;
            const int fa = f + (f >> 5);
            float2 o;
            o.x = mag[tg + 0][fa];
            o.y = mag[tg + 1][fa];
            *(float2*)&out[((size_t)b * F_C + f) * T_C + t0 + tg] = o;
        }
    } else {
        for (int e = tid; e < F_C * TT; e += 256) {
            const int f = e >> 3;
            const int tt = e & 7;
            const int t = t0 + tt;
            if (t < T_C)
                out[((size_t)b * F_C + f) * T_C + t] = mag[tt][f + (f >> 5)];
        }
    }
}

extern "C" void kernel_launch(void* const* d_in, const int* in_sizes, int n_in,
                              void* d_out, int out_size, void* d_ws, size_t ws_size,
                              hipStream_t stream) {
    const float* x   = (const float*)d_in[0];
    const float* wl  = (const float*)d_in[1];
    const float* st  = (const float*)d_in[2];
    const float* wp  = (const float*)d_in[3];
    float* out = (float*)d_out;
    float* tap = (float*)d_ws;   // T_C*NN floats ~ 2.55 MB

    win_kernel<<<dim3(T_C), dim3(256), 0, stream>>>(wl, st, wp, tap);
    fftw_kernel<<<dim3(B_C * NTILE), dim3(256), 0, stream>>>(x, st, tap, out);
}

// Round 15
// 73.710 us; speedup vs baseline: 1.9817x; 1.0331x over previous
//
#include <hip/hip_runtime.h>
#include <math.h>

#define NN 1024
#define B_C 64
#define L_C 160000
#define T_C 622
#define F_C 513
#define TT 16
#define NTILE ((T_C + TT - 1) / TT)   // 39
#define WIN_MIN_C (1024.0f / 20.0f)
#define WIN_MAX_C 1024.0f
#define TWO_PI 6.28318530717958647692f

typedef unsigned uv2 __attribute__((ext_vector_type(2)));

__device__ __forceinline__ int brev6(int x) {
    return ((x & 1) << 5) | ((x & 2) << 3) | ((x & 4) << 1) |
           ((x & 8) >> 1) | ((x & 16) >> 3) | ((x & 32) >> 5);
}

// ---- lane-exchange helpers ----
__device__ __forceinline__ float lane_xor32(float v, int l) {
#if __has_builtin(__builtin_amdgcn_permlane32_swap)
    uv2 r = __builtin_amdgcn_permlane32_swap(__float_as_uint(v), __float_as_uint(v),
                                             false, false);
    return __uint_as_float((l & 32) ? r.x : r.y);
#else
    return __shfl_xor(v, 32, 64);
#endif
}
__device__ __forceinline__ float lane_xor8(float v) {   // row_ror:8 == xor8
    return __int_as_float(__builtin_amdgcn_update_dpp(
        __float_as_int(v), __float_as_int(v), 0x128, 0xF, 0xF, false));
}
__device__ __forceinline__ float lane_xor4(float v) {   // ds_swizzle xor4
    return __int_as_float(__builtin_amdgcn_ds_swizzle(__float_as_int(v), 0x101F));
}
__device__ __forceinline__ float lane_xor2(float v) {   // quad_perm [2,3,0,1]
    return __int_as_float(__builtin_amdgcn_update_dpp(
        __float_as_int(v), __float_as_int(v), 0x4E, 0xF, 0xF, false));
}
__device__ __forceinline__ float lane_xor1(float v) {   // quad_perm [1,0,3,2]
    return __int_as_float(__builtin_amdgcn_update_dpp(
        __float_as_int(v), __float_as_int(v), 0xB1, 0xF, 0xF, false));
}
__device__ __forceinline__ float lane_xor31(float v) {  // ds_swizzle xor31
    return __int_as_float(__builtin_amdgcn_ds_swizzle(__float_as_int(v), 0x7C1F));
}
__device__ __forceinline__ float lane_xor63(float v, int l) {
    return lane_xor32(lane_xor31(v), l);   // 31 ^ 32 = 63, DS + VALU
}
__device__ __forceinline__ float fast_sqrtf(float x) {
#if __has_builtin(__builtin_amdgcn_sqrtf)
    return __builtin_amdgcn_sqrtf(x);
#else
    return sqrtf(x);
#endif
}

// ---------------- Kernel A: per-frame normalized Hann taps ----------------
// NOTE: stores 0.5 * normalized tap — folds the conjugate-unpack /2 scale
// into the table so the FFT kernel never multiplies by 0.5.
__global__ __launch_bounds__(256) void win_kernel(
    const float* __restrict__ win_length,
    const float* __restrict__ strides,
    const float* __restrict__ win_pow,
    float* __restrict__ tap)   // [T_C][NN]
{
    const int t = blockIdx.x;
    const int tid = threadIdx.x;

    const float wl = fminf(fmaxf(win_length[0], WIN_MIN_C), WIN_MAX_C);
    const float st = fminf(fmaxf(strides[0], 0.0f), WIN_MAX_C);
    const float wp = win_pow[0];

    const float frame = (float)t * st;
    const float frac = frame - floorf(frame);

    const float hi = ceilf(((float)NN - 1.0f + wl) * 0.5f);
    const float lo = floorf(((float)NN - 1.0f - wl) * 0.5f);
    const float off = (wl - (float)NN + 1.0f) * 0.5f;
    const float inv_wl = 1.0f / wl;

    __shared__ float s_tap[NN];
    __shared__ float s_red[256];

    float local = 0.0f;
    for (int n = tid; n < NN; n += 256) {
        float base = (float)n - frac;
        float v = 0.5f - 0.5f * cosf(TWO_PI * (base + off) * inv_wl);
        if (base >= hi || base <= lo) v = 0.0f;
        s_tap[n] = v;
        local += v;
    }
    s_red[tid] = local;
    __syncthreads();
    for (int s = 128; s > 0; s >>= 1) {
        if (tid < s) s_red[tid] += s_red[tid + s];
        __syncthreads();
    }
    const float inv_sum = 1.0f / s_red[0];
    const bool pow_one = (wp == 1.0f);
    for (int n = tid; n < NN; n += 256) {
        float v = s_tap[n] * inv_sum;
        if (!pow_one) v = powf(v, wp);
        tap[t * NN + n] = 0.5f * v;
    }
}

// --- Kernel B: 8 waves/block, wave-per-packed-FFT, fold-twiddle lane FFT ---
__global__ __launch_bounds__(512, 4) void fftw_kernel(
    const float* __restrict__ x,        // [B_C][L_C]
    const float* __restrict__ strides,
    const float* __restrict__ tap,      // [T_C][NN]  (pre-scaled by 0.5)
    float* __restrict__ out)            // [B_C][F_C][T_C]
{
    const int tile = blockIdx.x % NTILE;
    const int b = blockIdx.x / NTILE;
    const int t0 = tile * TT;
    const int tid = threadIdx.x;
    const int w = tid >> 6;      // wave id 0..7 = frame pair
    const int l = tid & 63;      // lane

    const float st = fminf(fmaxf(strides[0], 0.0f), WIN_MAX_C);
    const float* xb = x + (size_t)b * L_C;

    __shared__ float mag[TT][F_C + 16];   // 529-float rows: stride%32=17, coprime

    const int bl = brev6(l);
    const int l2 = brev6((64 - bl) & 63);   // unpack partner lane for k1==0 reg

    constexpr int BR4[16]     = {0,8,4,12,2,10,6,14,1,9,5,13,3,11,7,15};
    constexpr int PARTNER[16] = {0,1,3,2,7,6,5,4,15,14,13,12,11,10,9,8};
    constexpr float C16[8] = {1.0f, 0.92387953251f, 0.70710678119f, 0.38268343236f,
                              0.0f, -0.38268343236f, -0.70710678119f, -0.92387953251f};
    constexpr float S16[8] = {0.0f, -0.38268343236f, -0.70710678119f, -0.92387953251f,
                              -1.0f, -0.92387953251f, -0.70710678119f, -0.38268343236f};

    const int jp = w;                   // pair index 0..7
    const int tA = t0 + 2 * jp;
    const int tB = tA + 1;
    const bool hasA = (tA < T_C);
    const bool hasB = (tB < T_C);
    const int idxA = hasA ? (int)floorf((float)tA * st) : 0;
    const int idxB = hasB ? (int)floorf((float)tB * st) : 0;
    const float* tpA = tap + (size_t)tA * NN;
    const float* tpB = tap + (size_t)tB * NN;

    float vr[16], vi[16];

    // ---- load + taper: frame A -> re, frame B -> im; element n = 64*r + l
    const bool okA = hasA && (idxA >= 0) && (idxA + NN <= L_C);
    const bool okB = hasB && (idxB >= 0) && (idxB + NN <= L_C);
    if (okA && okB) {
#pragma unroll
        for (int r = 0; r < 16; ++r) {
            const int n = r * 64 + l;
            vr[r] = xb[idxA + n] * tpA[n];
            vi[r] = xb[idxB + n] * tpB[n];
        }
    } else {
#pragma unroll
        for (int r = 0; r < 16; ++r) {
            const int n = r * 64 + l;
            float a = 0.0f, bb = 0.0f;
            if (hasA) {
                int ia = idxA + n;
                a = (ia >= 0 && ia < L_C) ? xb[ia] * tpA[n] : 0.0f;
            }
            if (hasB) {
                int ib = idxB + n;
                bb = (ib >= 0 && ib < L_C) ? xb[ib] * tpB[n] : 0.0f;
            }
            vr[r] = a;
            vi[r] = bb;
        }
    }

    // ---- 16-point DIF FFT over registers (output i holds k1 = BR4[i])
#pragma unroll
    for (int s = 0; s < 4; ++s) {
        const int half = (16 >> s) >> 1;
#pragma unroll
        for (int b0 = 0; b0 < 16; b0 += (16 >> s)) {
#pragma unroll
            for (int j = 0; j < 8; ++j) {
                if (j < half) {
                    const int i0 = b0 + j, i1 = b0 + j + half;
                    const float ur = vr[i0], ui = vi[i0];
                    const float wr = vr[i1], wi = vi[i1];
                    vr[i0] = ur + wr; vi[i0] = ui + wi;
                    const float dr = ur - wr, di = ui - wi;
                    const float c = C16[j << s], ss = S16[j << s];
                    vr[i1] = dr * c - di * ss;
                    vi[i1] = dr * ss + di * c;
                }
            }
        }
    }

    // ---- twiddle W_1024^(l * k1): powers via doubling tree (log-depth, ILP)
    {
        float c1, s1;
        __sincosf(-(TWO_PI / 1024.0f) * (float)l, &s1, &c1);
        const float c2 = c1 * c1 - s1 * s1,  s2 = 2.0f * c1 * s1;
        const float c4 = c2 * c2 - s2 * s2,  s4 = 2.0f * c2 * s2;
        const float c8 = c4 * c4 - s4 * s4,  s8 = 2.0f * c4 * s4;
        const float c3 = c1 * c2 - s1 * s2,  s3 = c1 * s2 + s1 * c2;
        const float c5 = c1 * c4 - s1 * s4,  s5 = c1 * s4 + s1 * c4;
        const float c6 = c2 * c4 - s2 * s4,  s6 = c2 * s4 + s2 * c4;
        const float c7 = c3 * c4 - s3 * s4,  s7 = c3 * s4 + s3 * c4;
        const float c9  = c1 * c8 - s1 * s8, s9  = c1 * s8 + s1 * c8;
        const float c10 = c2 * c8 - s2 * s8, s10 = c2 * s8 + s2 * c8;
        const float c11 = c3 * c8 - s3 * s8, s11 = c3 * s8 + s3 * c8;
        const float c12 = c4 * c8 - s4 * s8, s12 = c4 * s8 + s4 * c8;
        const float c13 = c5 * c8 - s5 * s8, s13 = c5 * s8 + s5 * c8;
        const float c14 = c6 * c8 - s6 * s8, s14 = c6 * s8 + s6 * c8;
        const float c15 = c7 * c8 - s7 * s8, s15 = c7 * s8 + s7 * c8;
#define TW(K) { const int i_ = BR4[K]; const float ar = vr[i_], ai = vi[i_]; \
                vr[i_] = ar * c##K - ai * s##K; vi[i_] = ar * s##K + ai * c##K; }
        TW(1) TW(2) TW(3) TW(4) TW(5) TW(6) TW(7) TW(8)
        TW(9) TW(10) TW(11) TW(12) TW(13) TW(14) TW(15)
#undef TW
    }

    // ---- 64-point DIF FFT across lanes, fold-twiddle convention:
    //      d = v + sgn*p (high: v - p), angle -2*pi*l*2^s/64, 1 sincos total.
    {
        float cu, su;
        __sincosf(-(TWO_PI / 64.0f) * (float)l, &su, &cu);

        // --- stage 0: xor32 via permlane32_swap both-halves ---
        {
            const bool hi_ = (l & 32) != 0;
            const float sgn = hi_ ? -1.0f : 1.0f;
            const float tc = hi_ ? cu : 1.0f;
            const float ts = hi_ ? su : 0.0f;
            float dr[16], di[16];
#pragma unroll
            for (int i = 0; i < 16; ++i) {
#if __has_builtin(__builtin_amdgcn_permlane32_swap)
                uv2 xr = __builtin_amdgcn_permlane32_swap(
                    __float_as_uint(vr[i]), __float_as_uint(vr[i]), false, false);
                uv2 xi = __builtin_amdgcn_permlane32_swap(
                    __float_as_uint(vi[i]), __float_as_uint(vi[i]), false, false);
                dr[i] = fmaf(sgn, __uint_as_float(xr.x), __uint_as_float(xr.y));
                di[i] = fmaf(sgn, __uint_as_float(xi.x), __uint_as_float(xi.y));
#else
                dr[i] = fmaf(sgn, __shfl_xor(vr[i], 32, 64), vr[i]);
                di[i] = fmaf(sgn, __shfl_xor(vi[i], 32, 64), vi[i]);
#endif
            }
#pragma unroll
            for (int i = 0; i < 16; ++i) {
                vr[i] = dr[i] * tc - di[i] * ts;
                vi[i] = dr[i] * ts + di[i] * tc;
            }
            const float nc = fmaf(2.0f * cu, cu, -1.0f);
            su = 2.0f * cu * su; cu = nc;
        }
        // --- stage 1: xor16 via permlane16_swap both-halves ---
        {
            const bool hi_ = (l & 16) != 0;
            const float sgn = hi_ ? -1.0f : 1.0f;
            const float tc = hi_ ? cu : 1.0f;
            const float ts = hi_ ? su : 0.0f;
            float dr[16], di[16];
#pragma unroll
            for (int i = 0; i < 16; ++i) {
#if __has_builtin(__builtin_amdgcn_permlane16_swap)
                uv2 xr = __builtin_amdgcn_permlane16_swap(
                    __float_as_uint(vr[i]), __float_as_uint(vr[i]), false, false);
                uv2 xi = __builtin_amdgcn_permlane16_swap(
                    __float_as_uint(vi[i]), __float_as_uint(vi[i]), false, false);
                dr[i] = fmaf(sgn, __uint_as_float(xr.x), __uint_as_float(xr.y));
                di[i] = fmaf(sgn, __uint_as_float(xi.x), __uint_as_float(xi.y));
#else
                dr[i] = fmaf(sgn, __shfl_xor(vr[i], 16, 64), vr[i]);
                di[i] = fmaf(sgn, __shfl_xor(vi[i], 16, 64), vi[i]);
#endif
            }
#pragma unroll
            for (int i = 0; i < 16; ++i) {
                vr[i] = dr[i] * tc - di[i] * ts;
                vi[i] = dr[i] * ts + di[i] * tc;
            }
            const float nc = fmaf(2.0f * cu, cu, -1.0f);
            su = 2.0f * cu * su; cu = nc;
        }
        // --- stages 2..4: xor8 (DPP), xor4 (swizzle), xor2 (DPP) ---
#define FOLD_STAGE(MASK, EXCH)                                                \
        {                                                                     \
            const bool hi_ = (l & (MASK)) != 0;                               \
            const float sgn = hi_ ? -1.0f : 1.0f;                             \
            const float tc = hi_ ? cu : 1.0f;                                 \
            const float ts = hi_ ? su : 0.0f;                                 \
            float dr[16], di[16];                                             \
            _Pragma("unroll")                                                 \
            for (int i = 0; i < 16; ++i) {                                    \
                dr[i] = fmaf(sgn, EXCH(vr[i]), vr[i]);                        \
                di[i] = fmaf(sgn, EXCH(vi[i]), vi[i]);                        \
            }                                                                 \
            _Pragma("unroll")                                                 \
            for (int i = 0; i < 16; ++i) {                                    \
                vr[i] = dr[i] * tc - di[i] * ts;                              \
                vi[i] = dr[i] * ts + di[i] * tc;                              \
            }                                                                 \
            const float nc = fmaf(2.0f * cu, cu, -1.0f);                      \
            su = 2.0f * cu * su; cu = nc;                                     \
        }
        FOLD_STAGE(8, lane_xor8)
        FOLD_STAGE(4, lane_xor4)
        FOLD_STAGE(2, lane_xor2)
#undef FOLD_STAGE
        // --- stage 5: xor1, twiddle == 1 -> plain butterfly ---
        {
            const float sgn = (l & 1) ? -1.0f : 1.0f;
#pragma unroll
            for (int i = 0; i < 16; ++i) {
                vr[i] = fmaf(sgn, vr[i], lane_xor1(vr[i]));
                vi[i] = fmaf(sgn, vi[i], lane_xor1(vi[i]));
            }
        }
    }
    // now (lane l, reg i) holds X[k'], k' = BR4[i] + 16*brev6(l)

    // ---- conjugate-symmetry unpack + magnitudes (all lanes productive):
    // low lane (k'<512) computes |A[k']|; high lane (k'>512) computes
    // |B[1024-k']| via t1=z.r+sgn*y.r, t2=z.i-sgn*y.i (sign dies in square).
    {
        // i = 0 (k1 == 0): contains self-mirrored k'=0 and k'=512 -> old path
        {
            const float yr = __shfl(vr[0], l2, 64);
            const float yi = __shfl(vi[0], l2, 64);
            const int k = 16 * bl;
            if (k <= 512) {
                const float sa = vr[0] + yr, sb = vi[0] - yi;
                const float ua = vi[0] + yi, ub = yr - vr[0];
                const int ka = k + (k >> 5);
                if (hasA) mag[2 * jp][ka] = fast_sqrtf(fmaf(sa, sa, sb * sb));
                if (hasB) mag[2 * jp + 1][ka] = fast_sqrtf(fmaf(ua, ua, ub * ub));
            }
        }
#pragma unroll
        for (int i = 1; i < 16; ++i) {
            const float yr = lane_xor63(vr[PARTNER[i]], l);
            const float yi = lane_xor63(vi[PARTNER[i]], l);
            const int kp = BR4[i] + 16 * bl;     // k' != 0, != 512 for i>=1
            const bool low = kp < 512;
            const float sgn = low ? 1.0f : -1.0f;
            const float t1 = fmaf(sgn, yr, vr[i]);
            const float t2 = fmaf(-sgn, yi, vi[i]);
            const float m = fast_sqrtf(fmaf(t1, t1, t2 * t2));
            const int k = low ? kp : (NN - kp);
            const int ka = k + (k >> 5);
            if (low ? hasA : hasB) mag[2 * jp + (low ? 0 : 1)][ka] = m;
        }
    }

    __syncthreads();

    // ---- coalesced write-out: float2 along t (622 even -> 8B aligned)
    if (t0 + TT <= T_C) {
        for (int q = tid; q < F_C * 8; q += 512) {
            const int f = q >> 3;
            const int tg = (q & 7) << 1;
            const int fa = f + (f >> 5);
            float2 o;
            o.x = mag[tg + 0][fa];
            o.y = mag[tg + 1][fa];
            *(float2*)&out[((size_t)b * F_C + f) * T_C + t0 + tg] = o;
        }
    } else {
        for (int e = tid; e < F_C * TT; e += 512) {
            const int f = e >> 4;
            const int tt = e & 15;
            const int t = t0 + tt;
            if (t < T_C)
                out[((size_t)b * F_C + f) * T_C + t] = mag[tt][f + (f >> 5)];
        }
    }
}

extern "C" void kernel_launch(void* const* d_in, const int* in_sizes, int n_in,
                              void* d_out, int out_size, void* d_ws, size_t ws_size,
                              hipStream_t stream) {
    const float* x   = (const float*)d_in[0];
    const float* wl  = (const float*)d_in[1];
    const float* st  = (const float*)d_in[2];
    const float* wp  = (const float*)d_in[3];
    float* out = (float*)d_out;
    float* tap = (float*)d_ws;   // T_C*NN floats ~ 2.55 MB

    win_kernel<<<dim3(T_C), dim3(256), 0, stream>>>(wl, st, wp, tap);
    fftw_kernel<<<dim3(B_C * NTILE), dim3(512), 0, stream>>>(x, st, tap, out);
}

// Round 16
// 72.405 us; speedup vs baseline: 2.0174x; 1.0180x over previous
//
#include <hip/hip_runtime.h>
#include <math.h>

#define NN 1024
#define B_C 64
#define L_C 160000
#define T_C 622
#define F_C 513
#define TT 16
#define NTILE ((T_C + TT - 1) / TT)   // 39
#define WIN_MIN_C (1024.0f / 20.0f)
#define WIN_MAX_C 1024.0f
#define TWO_PI 6.28318530717958647692f

typedef unsigned uv2 __attribute__((ext_vector_type(2)));
typedef float v2f __attribute__((ext_vector_type(2)));

__device__ __forceinline__ int brev6(int x) {
    return ((x & 1) << 5) | ((x & 2) << 3) | ((x & 4) << 1) |
           ((x & 8) >> 1) | ((x & 16) >> 3) | ((x & 32) >> 5);
}

// packed complex multiply: r = d * (cs.x + i*cs.y); d = {re, im}.
// t = {d.lo*c, d.hi*c}; r = {-d.hi*s + t.lo, d.lo*s + t.hi}. 2 VOP3P ops.
__device__ __forceinline__ v2f cmul_pk(v2f d, v2f cs) {
    v2f t, r;
    asm("v_pk_mul_f32 %0, %1, %2 op_sel_hi:[1,0]"
        : "=v"(t) : "v"(d), "v"(cs));
    asm("v_pk_fma_f32 %0, %1, %2, %3 op_sel:[1,1,0] op_sel_hi:[0,1,1] neg_lo:[1,0,0]"
        : "=v"(r) : "v"(d), "v"(cs), "v"(t));
    return r;
}

// ---- lane-exchange helpers ----
__device__ __forceinline__ float lane_xor32(float v, int l) {
#if __has_builtin(__builtin_amdgcn_permlane32_swap)
    uv2 r = __builtin_amdgcn_permlane32_swap(__float_as_uint(v), __float_as_uint(v),
                                             false, false);
    return __uint_as_float((l & 32) ? r.x : r.y);
#else
    return __shfl_xor(v, 32, 64);
#endif
}
__device__ __forceinline__ float lane_xor8(float v) {   // row_ror:8 == xor8
    return __int_as_float(__builtin_amdgcn_update_dpp(
        __float_as_int(v), __float_as_int(v), 0x128, 0xF, 0xF, false));
}
__device__ __forceinline__ float lane_xor4(float v) {   // ds_swizzle xor4
    return __int_as_float(__builtin_amdgcn_ds_swizzle(__float_as_int(v), 0x101F));
}
__device__ __forceinline__ float lane_xor2(float v) {   // quad_perm [2,3,0,1]
    return __int_as_float(__builtin_amdgcn_update_dpp(
        __float_as_int(v), __float_as_int(v), 0x4E, 0xF, 0xF, false));
}
__device__ __forceinline__ float lane_xor1(float v) {   // quad_perm [1,0,3,2]
    return __int_as_float(__builtin_amdgcn_update_dpp(
        __float_as_int(v), __float_as_int(v), 0xB1, 0xF, 0xF, false));
}
__device__ __forceinline__ float lane_xor31(float v) {  // ds_swizzle xor31
    return __int_as_float(__builtin_amdgcn_ds_swizzle(__float_as_int(v), 0x7C1F));
}
__device__ __forceinline__ float lane_xor63(float v, int l) {
    return lane_xor32(lane_xor31(v), l);   // 31 ^ 32 = 63, DS + VALU
}
__device__ __forceinline__ float fast_sqrtf(float x) {
#if __has_builtin(__builtin_amdgcn_sqrtf)
    return __builtin_amdgcn_sqrtf(x);
#else
    return sqrtf(x);
#endif
}

// ---------------- Kernel A: per-frame normalized Hann taps ----------------
// stores 0.5 * normalized tap (folds the conjugate-unpack /2 scale).
__global__ __launch_bounds__(256) void win_kernel(
    const float* __restrict__ win_length,
    const float* __restrict__ strides,
    const float* __restrict__ win_pow,
    float* __restrict__ tap)   // [T_C][NN]
{
    const int t = blockIdx.x;
    const int tid = threadIdx.x;

    const float wl = fminf(fmaxf(win_length[0], WIN_MIN_C), WIN_MAX_C);
    const float st = fminf(fmaxf(strides[0], 0.0f), WIN_MAX_C);
    const float wp = win_pow[0];

    const float frame = (float)t * st;
    const float frac = frame - floorf(frame);

    const float hi = ceilf(((float)NN - 1.0f + wl) * 0.5f);
    const float lo = floorf(((float)NN - 1.0f - wl) * 0.5f);
    const float off = (wl - (float)NN + 1.0f) * 0.5f;
    const float inv_wl = 1.0f / wl;

    __shared__ float s_tap[NN];
    __shared__ float s_red[256];

    float local = 0.0f;
    for (int n = tid; n < NN; n += 256) {
        float base = (float)n - frac;
        float v = 0.5f - 0.5f * cosf(TWO_PI * (base + off) * inv_wl);
        if (base >= hi || base <= lo) v = 0.0f;
        s_tap[n] = v;
        local += v;
    }
    s_red[tid] = local;
    __syncthreads();
    for (int s = 128; s > 0; s >>= 1) {
        if (tid < s) s_red[tid] += s_red[tid + s];
        __syncthreads();
    }
    const float inv_sum = 1.0f / s_red[0];
    const bool pow_one = (wp == 1.0f);
    for (int n = tid; n < NN; n += 256) {
        float v = s_tap[n] * inv_sum;
        if (!pow_one) v = powf(v, wp);
        tap[t * NN + n] = 0.5f * v;
    }
}

// --- Kernel B: 8 waves/block, packed-fp32 (VOP3P) FFT, fold twiddles ---
__global__ __launch_bounds__(512, 4) void fftw_kernel(
    const float* __restrict__ x,        // [B_C][L_C]
    const float* __restrict__ strides,
    const float* __restrict__ tap,      // [T_C][NN]  (pre-scaled by 0.5)
    float* __restrict__ out)            // [B_C][F_C][T_C]
{
    const int tile = blockIdx.x % NTILE;
    const int b = blockIdx.x / NTILE;
    const int t0 = tile * TT;
    const int tid = threadIdx.x;
    const int w = tid >> 6;      // wave id 0..7 = frame pair
    const int l = tid & 63;      // lane

    const float st = fminf(fmaxf(strides[0], 0.0f), WIN_MAX_C);
    const float* xb = x + (size_t)b * L_C;

    __shared__ float mag[TT][F_C + 16];   // 529-float rows: stride%32=17, coprime

    const int bl = brev6(l);
    const int l2 = brev6((64 - bl) & 63);   // unpack partner lane for k1==0 reg

    constexpr int BR4[16]     = {0,8,4,12,2,10,6,14,1,9,5,13,3,11,7,15};
    constexpr int PARTNER[16] = {0,1,3,2,7,6,5,4,15,14,13,12,11,10,9,8};
    constexpr float C16[8] = {1.0f, 0.92387953251f, 0.70710678119f, 0.38268343236f,
                              0.0f, -0.38268343236f, -0.70710678119f, -0.92387953251f};
    constexpr float S16[8] = {0.0f, -0.38268343236f, -0.70710678119f, -0.92387953251f,
                              -1.0f, -0.92387953251f, -0.70710678119f, -0.38268343236f};

    const int jp = w;                   // pair index 0..7
    const int tA = t0 + 2 * jp;
    const int tB = tA + 1;
    const bool hasA = (tA < T_C);
    const bool hasB = (tB < T_C);
    const int idxA = hasA ? (int)floorf((float)tA * st) : 0;
    const int idxB = hasB ? (int)floorf((float)tB * st) : 0;
    const float* tpA = tap + (size_t)tA * NN;
    const float* tpB = tap + (size_t)tB * NN;

    v2f v[16];   // v[i].x = frame A (re), v[i].y = frame B (im)

    // ---- load + taper; wave-uniform in-bounds fast path
    const bool okA = hasA && (idxA >= 0) && (idxA + NN <= L_C);
    const bool okB = hasB && (idxB >= 0) && (idxB + NN <= L_C);
    if (okA && okB) {
#pragma unroll
        for (int r = 0; r < 16; ++r) {
            const int n = r * 64 + l;
            v[r].x = xb[idxA + n] * tpA[n];
            v[r].y = xb[idxB + n] * tpB[n];
        }
    } else {
#pragma unroll
        for (int r = 0; r < 16; ++r) {
            const int n = r * 64 + l;
            float a = 0.0f, bb = 0.0f;
            if (hasA) {
                int ia = idxA + n;
                a = (ia >= 0 && ia < L_C) ? xb[ia] * tpA[n] : 0.0f;
            }
            if (hasB) {
                int ib = idxB + n;
                bb = (ib >= 0 && ib < L_C) ? xb[ib] * tpB[n] : 0.0f;
            }
            v[r].x = a;
            v[r].y = bb;
        }
    }

    // ---- 16-point DIF FFT over registers, packed (output i holds k1=BR4[i])
#pragma unroll
    for (int s = 0; s < 4; ++s) {
        const int half = (16 >> s) >> 1;
#pragma unroll
        for (int b0 = 0; b0 < 16; b0 += (16 >> s)) {
#pragma unroll
            for (int j = 0; j < 8; ++j) {
                if (j < half) {
                    const int i0 = b0 + j, i1 = b0 + j + half;
                    const v2f u = v[i0], ww = v[i1];
                    v[i0] = u + ww;                 // v_pk_add_f32
                    const v2f d = u - ww;           // v_pk_add_f32 (neg)
                    if ((j << s) == 0) {
                        v[i1] = d;
                    } else {
                        v2f cs;
                        cs.x = C16[j << s];
                        cs.y = S16[j << s];
                        v[i1] = cmul_pk(d, cs);
                    }
                }
            }
        }
    }

    // ---- twiddle W_1024^(l * k1): doubling tree, packed cmul apply
    {
        float c1, s1;
        __sincosf(-(TWO_PI / 1024.0f) * (float)l, &s1, &c1);
        const float c2 = c1 * c1 - s1 * s1,  s2 = 2.0f * c1 * s1;
        const float c4 = c2 * c2 - s2 * s2,  s4 = 2.0f * c2 * s2;
        const float c8 = c4 * c4 - s4 * s4,  s8 = 2.0f * c4 * s4;
        const float c3 = c1 * c2 - s1 * s2,  s3 = c1 * s2 + s1 * c2;
        const float c5 = c1 * c4 - s1 * s4,  s5 = c1 * s4 + s1 * c4;
        const float c6 = c2 * c4 - s2 * s4,  s6 = c2 * s4 + s2 * c4;
        const float c7 = c3 * c4 - s3 * s4,  s7 = c3 * s4 + s3 * c4;
        const float c9  = c1 * c8 - s1 * s8, s9  = c1 * s8 + s1 * c8;
        const float c10 = c2 * c8 - s2 * s8, s10 = c2 * s8 + s2 * c8;
        const float c11 = c3 * c8 - s3 * s8, s11 = c3 * s8 + s3 * c8;
        const float c12 = c4 * c8 - s4 * s8, s12 = c4 * s8 + s4 * c8;
        const float c13 = c5 * c8 - s5 * s8, s13 = c5 * s8 + s5 * c8;
        const float c14 = c6 * c8 - s6 * s8, s14 = c6 * s8 + s6 * c8;
        const float c15 = c7 * c8 - s7 * s8, s15 = c7 * s8 + s7 * c8;
#define TW(K) { v2f cs; cs.x = c##K; cs.y = s##K; \
                v[BR4[K]] = cmul_pk(v[BR4[K]], cs); }
        TW(1) TW(2) TW(3) TW(4) TW(5) TW(6) TW(7) TW(8)
        TW(9) TW(10) TW(11) TW(12) TW(13) TW(14) TW(15)
#undef TW
    }

    // ---- 64-point DIF FFT across lanes, fold-twiddle convention:
    //      d = v + sgn*p (high: v - p), angle -2*pi*l*2^s/64, 1 sincos total.
    {
        float cu, su;
        __sincosf(-(TWO_PI / 64.0f) * (float)l, &su, &cu);

        // --- stage 0: xor32 via permlane32_swap both-halves ---
        {
            const bool hi_ = (l & 32) != 0;
            const float sgn = hi_ ? -1.0f : 1.0f;
            v2f tcs; tcs.x = hi_ ? cu : 1.0f; tcs.y = hi_ ? su : 0.0f;
#pragma unroll
            for (int i = 0; i < 16; ++i) {
                v2f d;
#if __has_builtin(__builtin_amdgcn_permlane32_swap)
                uv2 xr = __builtin_amdgcn_permlane32_swap(
                    __float_as_uint(v[i].x), __float_as_uint(v[i].x), false, false);
                uv2 xi = __builtin_amdgcn_permlane32_swap(
                    __float_as_uint(v[i].y), __float_as_uint(v[i].y), false, false);
                d.x = fmaf(sgn, __uint_as_float(xr.x), __uint_as_float(xr.y));
                d.y = fmaf(sgn, __uint_as_float(xi.x), __uint_as_float(xi.y));
#else
                d.x = fmaf(sgn, __shfl_xor(v[i].x, 32, 64), v[i].x);
                d.y = fmaf(sgn, __shfl_xor(v[i].y, 32, 64), v[i].y);
#endif
                v[i] = cmul_pk(d, tcs);
            }
            const float nc = fmaf(2.0f * cu, cu, -1.0f);
            su = 2.0f * cu * su; cu = nc;
        }
        // --- stage 1: xor16 via permlane16_swap both-halves ---
        {
            const bool hi_ = (l & 16) != 0;
            const float sgn = hi_ ? -1.0f : 1.0f;
            v2f tcs; tcs.x = hi_ ? cu : 1.0f; tcs.y = hi_ ? su : 0.0f;
#pragma unroll
            for (int i = 0; i < 16; ++i) {
                v2f d;
#if __has_builtin(__builtin_amdgcn_permlane16_swap)
                uv2 xr = __builtin_amdgcn_permlane16_swap(
                    __float_as_uint(v[i].x), __float_as_uint(v[i].x), false, false);
                uv2 xi = __builtin_amdgcn_permlane16_swap(
                    __float_as_uint(v[i].y), __float_as_uint(v[i].y), false, false);
                d.x = fmaf(sgn, __uint_as_float(xr.x), __uint_as_float(xr.y));
                d.y = fmaf(sgn, __uint_as_float(xi.x), __uint_as_float(xi.y));
#else
                d.x = fmaf(sgn, __shfl_xor(v[i].x, 16, 64), v[i].x);
                d.y = fmaf(sgn, __shfl_xor(v[i].y, 16, 64), v[i].y);
#endif
                v[i] = cmul_pk(d, tcs);
            }
            const float nc = fmaf(2.0f * cu, cu, -1.0f);
            su = 2.0f * cu * su; cu = nc;
        }
        // --- stages 2..4: xor8 (DPP), xor4 (swizzle), xor2 (DPP) ---
#define FOLD_STAGE(MASK, EXCH)                                                \
        {                                                                     \
            const bool hi_ = (l & (MASK)) != 0;                               \
            const float sgn = hi_ ? -1.0f : 1.0f;                             \
            v2f tcs; tcs.x = hi_ ? cu : 1.0f; tcs.y = hi_ ? su : 0.0f;        \
            _Pragma("unroll")                                                 \
            for (int i = 0; i < 16; ++i) {                                    \
                v2f d;                                                        \
                d.x = fmaf(sgn, EXCH(v[i].x), v[i].x);                        \
                d.y = fmaf(sgn, EXCH(v[i].y), v[i].y);                        \
                v[i] = cmul_pk(d, tcs);                                       \
            }                                                                 \
            const float nc = fmaf(2.0f * cu, cu, -1.0f);                      \
            su = 2.0f * cu * su; cu = nc;                                     \
        }
        FOLD_STAGE(8, lane_xor8)
        FOLD_STAGE(4, lane_xor4)
        FOLD_STAGE(2, lane_xor2)
#undef FOLD_STAGE
        // --- stage 5: xor1, twiddle == 1 -> plain butterfly ---
        {
            const float sgn = (l & 1) ? -1.0f : 1.0f;
#pragma unroll
            for (int i = 0; i < 16; ++i) {
                v[i].x = fmaf(sgn, v[i].x, lane_xor1(v[i].x));
                v[i].y = fmaf(sgn, v[i].y, lane_xor1(v[i].y));
            }
        }
    }
    // now (lane l, reg i) holds X[k'], k' = BR4[i] + 16*brev6(l)

    // ---- conjugate-symmetry unpack + magnitudes (all lanes productive)
    {
        // i = 0 (k1 == 0): self-mirrored k'=0 / k'=512 -> paired path
        {
            const float yr = __shfl(v[0].x, l2, 64);
            const float yi = __shfl(v[0].y, l2, 64);
            const int k = 16 * bl;
            if (k <= 512) {
                const float sa = v[0].x + yr, sb = v[0].y - yi;
                const float ua = v[0].y + yi, ub = yr - v[0].x;
                const int ka = k + (k >> 5);
                if (hasA) mag[2 * jp][ka] = fast_sqrtf(fmaf(sa, sa, sb * sb));
                if (hasB) mag[2 * jp + 1][ka] = fast_sqrtf(fmaf(ua, ua, ub * ub));
            }
        }
        // i >= 1: low lane (bl<32, i.e. l even) -> |A[k']|; high -> |B[1024-k']|
        const bool lowk = (bl < 32);
        v2f sp; sp.x = lowk ? 1.0f : -1.0f; sp.y = lowk ? -1.0f : 1.0f;
        const int row = 2 * jp + (lowk ? 0 : 1);
        const bool wr_ok = lowk ? hasA : hasB;
#pragma unroll
        for (int i = 1; i < 16; ++i) {
            v2f y;
            y.x = lane_xor63(v[PARTNER[i]].x, l);
            y.y = lane_xor63(v[PARTNER[i]].y, l);
            const v2f t = y * sp + v[i];            // {t1, t2} packed fma
            const float m = fast_sqrtf(fmaf(t.x, t.x, t.y * t.y));
            const int kp = BR4[i] + 16 * bl;
            const int k = lowk ? kp : (NN - kp);
            const int ka = k + (k >> 5);
            if (wr_ok) mag[row][ka] = m;
        }
    }

    __syncthreads();

    // ---- coalesced write-out: float2 along t (622 even -> 8B aligned)
    if (t0 + TT <= T_C) {
        for (int q = tid; q < F_C * 8; q += 512) {
            const int f = q >> 3;
            const int tg = (q & 7) << 1;
            const int fa = f + (f >> 5);
            float2 o;
            o.x = mag[tg + 0][fa];
            o.y = mag[tg + 1][fa];
            *(float2*)&out[((size_t)b * F_C + f) * T_C + t0 + tg] = o;
        }
    } else {
        for (int e = tid; e < F_C * TT; e += 512) {
            const int f = e >> 4;
            const int tt = e & 15;
            const int t = t0 + tt;
            if (t < T_C)
                out[((size_t)b * F_C + f) * T_C + t] = mag[tt][f + (f >> 5)];
        }
    }
}

extern "C" void kernel_launch(void* const* d_in, const int* in_sizes, int n_in,
                              void* d_out, int out_size, void* d_ws, size_t ws_size,
                              hipStream_t stream) {
    const float* x   = (const float*)d_in[0];
    const float* wl  = (const float*)d_in[1];
    const float* st  = (const float*)d_in[2];
    const float* wp  = (const float*)d_in[3];
    float* out = (float*)d_out;
    float* tap = (float*)d_ws;   // T_C*NN floats ~ 2.55 MB

    win_kernel<<<dim3(T_C), dim3(256), 0, stream>>>(wl, st, wp, tap);
    fftw_kernel<<<dim3(B_C * NTILE), dim3(512), 0, stream>>>(x, st, tap, out);
}